// Round 1
// baseline (4542.807 us; speedup 1.0000x reference)
//
#include <hip/hip_runtime.h>
#include <math.h>

// Problem constants (from reference)
#define Bn 32
#define Nn 256
#define IDIM 2048
#define PDIM 768
#define VDIM 1024
#define SDIM 8
#define D2 (IDIM + PDIM)   // 2816
#define Mrows (Bn * Nn)    // 8192
#define EPSN 1e-8f
#define LNEPS 1e-5f
#define THRESH 0.5f

// ---------------------------------------------------------------------------
// Row L2 norms of concat(image, pc) rows. grid=(8192,2): y=0 current, y=1 prev
// ---------------------------------------------------------------------------
__global__ __launch_bounds__(256) void rownorm_k(
    const float* __restrict__ i1, const float* __restrict__ p1,
    const float* __restrict__ i2, const float* __restrict__ p2,
    float* __restrict__ nf, float* __restrict__ np_)
{
    const int row = blockIdx.x;
    const float* A = blockIdx.y ? i2 : i1;
    const float* P = blockIdx.y ? p2 : p1;
    float s = 0.f;
    const float4* a4 = (const float4*)(A + (size_t)row * IDIM);
    for (int t = threadIdx.x; t < IDIM / 4; t += 256) {
        float4 v = a4[t];
        s += v.x * v.x + v.y * v.y + v.z * v.z + v.w * v.w;
    }
    const float4* p4 = (const float4*)(P + (size_t)row * PDIM);
    for (int t = threadIdx.x; t < PDIM / 4; t += 256) {
        float4 v = p4[t];
        s += v.x * v.x + v.y * v.y + v.z * v.z + v.w * v.w;
    }
    for (int o = 32; o; o >>= 1) s += __shfl_down(s, o, 64);
    __shared__ float lds[4];
    if ((threadIdx.x & 63) == 0) lds[threadIdx.x >> 6] = s;
    __syncthreads();
    if (threadIdx.x == 0) {
        float t = lds[0] + lds[1] + lds[2] + lds[3];
        (blockIdx.y ? np_ : nf)[row] = sqrtf(t);
    }
}

// ---------------------------------------------------------------------------
// sim[b][i][j] = dot(feat[b,i], prev[b,j]) / (max(nf,EPS)*max(np,EPS))
// 64x64 tile per block, BK=16. grid=(4,4,32), 256 threads.
// ---------------------------------------------------------------------------
__global__ __launch_bounds__(256) void sim_k(
    const float* __restrict__ img, const float* __restrict__ pc,
    const float* __restrict__ pimg, const float* __restrict__ ppc,
    const float* __restrict__ nf, const float* __restrict__ np_,
    float* __restrict__ sim)
{
    __shared__ float As[16][68];
    __shared__ float Bs[16][68];
    const int b  = blockIdx.z;
    const int i0 = blockIdx.y * 64;
    const int j0 = blockIdx.x * 64;
    const int tid = threadIdx.x;
    const int tn = tid & 15, tm = tid >> 4;
    float acc[4][4] = {};

    const int m  = tid >> 2;      // 0..63
    const int kq = tid & 3;       // 0..3

    for (int k0 = 0; k0 < D2; k0 += 16) {
        int gcol = k0 + kq * 4;
        float4 v, u;
        if (gcol < IDIM) {
            v = *(const float4*)(img  + ((size_t)(b * Nn + i0 + m)) * IDIM + gcol);
            u = *(const float4*)(pimg + ((size_t)(b * Nn + j0 + m)) * IDIM + gcol);
        } else {
            v = *(const float4*)(pc  + ((size_t)(b * Nn + i0 + m)) * PDIM + (gcol - IDIM));
            u = *(const float4*)(ppc + ((size_t)(b * Nn + j0 + m)) * PDIM + (gcol - IDIM));
        }
        As[kq * 4 + 0][m] = v.x; As[kq * 4 + 1][m] = v.y;
        As[kq * 4 + 2][m] = v.z; As[kq * 4 + 3][m] = v.w;
        Bs[kq * 4 + 0][m] = u.x; Bs[kq * 4 + 1][m] = u.y;
        Bs[kq * 4 + 2][m] = u.z; Bs[kq * 4 + 3][m] = u.w;
        __syncthreads();
#pragma unroll
        for (int k = 0; k < 16; ++k) {
            float a[4], w[4];
            *(float4*)a = *(const float4*)&As[k][tm * 4];
            *(float4*)w = *(const float4*)&Bs[k][tn * 4];
#pragma unroll
            for (int r = 0; r < 4; ++r)
#pragma unroll
                for (int c = 0; c < 4; ++c) acc[r][c] += a[r] * w[c];
        }
        __syncthreads();
    }
    float sj[4];
#pragma unroll
    for (int c = 0; c < 4; ++c) sj[c] = 1.f / fmaxf(np_[b * Nn + j0 + tn * 4 + c], EPSN);
#pragma unroll
    for (int r = 0; r < 4; ++r) {
        int i = i0 + tm * 4 + r;
        float si = 1.f / fmaxf(nf[b * Nn + i], EPSN);
        float4 o;
        o.x = acc[r][0] * si * sj[0];
        o.y = acc[r][1] * si * sj[1];
        o.z = acc[r][2] * si * sj[2];
        o.w = acc[r][3] * si * sj[3];
        *(float4*)(sim + ((size_t)b * Nn + i) * Nn + j0 + tn * 4) = o;
    }
}

// ---------------------------------------------------------------------------
// Greedy match. One block per batch, 256 threads (thread j = candidate).
// Writes midx[b*N+i] (-1 if none) and new_prev_spatial into d_out.
// ---------------------------------------------------------------------------
__global__ __launch_bounds__(256) void match_k(
    const float* __restrict__ sim, const int* __restrict__ mask,
    const float* __restrict__ psp, int* __restrict__ midx,
    float* __restrict__ osp)
{
    const int b = blockIdx.x;
    const int j = threadIdx.x;
    const int lane = j & 63, wid = j >> 6;
    __shared__ int vis[256];
    __shared__ unsigned long long wb[4];
    __shared__ float wv[4];
    __shared__ int wi[4];
    __shared__ int fidx_s;
    vis[j] = 0;
    __syncthreads();
    for (int i = 0; i < Nn; ++i) {
        size_t off = ((size_t)b * Nn + i) * Nn + j;
        float s = sim[off];
        int mk = mask[off];
        bool valid = mk && (!vis[j]) && (s >= THRESH);
        unsigned long long bal = __ballot(valid);
        if (lane == 0) wb[wid] = bal;
        __syncthreads();
        bool found = (wb[0] | wb[1] | wb[2] | wb[3]) != 0ULL;
        if (found) {
            float v = valid ? s : -INFINITY;
            int idx = j;
            for (int o = 32; o; o >>= 1) {
                float v2 = __shfl_down(v, o, 64);
                int i2 = __shfl_down(idx, o, 64);
                if (v2 > v || (v2 == v && i2 < idx)) { v = v2; idx = i2; }
            }
            if (lane == 0) { wv[wid] = v; wi[wid] = idx; }
            __syncthreads();
            if (j == 0) {
                float bv = wv[0]; int bi = wi[0];
                for (int w = 1; w < 4; ++w)
                    if (wv[w] > bv || (wv[w] == bv && wi[w] < bi)) { bv = wv[w]; bi = wi[w]; }
                fidx_s = bi;
                vis[bi] = 1;
                midx[b * Nn + i] = bi;
            }
            __syncthreads();
            int fi = fidx_s;
            if (j < SDIM)
                osp[((size_t)b * Nn + i) * SDIM + j] = psp[((size_t)b * Nn + fi) * SDIM + j];
        } else {
            if (j == 0) midx[b * Nn + i] = -1;
            if (j < SDIM) osp[((size_t)b * Nn + i) * SDIM + j] = 0.f;
        }
        __syncthreads();
    }
}

// ---------------------------------------------------------------------------
// SGEMM: C[M][No] = act(A[M][K] @ W[K][No] + bias)
// MODE 0: A plain. MODE 1: A = concat(X1[b,i,:K1], gather(X2, midx)[b,i,:K-K1])
// 128x128 tile, BK=16, 256 threads, 8x8/thread in 2x2 quadrants.
// ---------------------------------------------------------------------------
template <int MODE, int RELU>
__global__ __launch_bounds__(256) void gemm_k(
    const float* __restrict__ A, const float* __restrict__ X1,
    const float* __restrict__ X2, const int* __restrict__ midx,
    int K, int K1,
    const float* __restrict__ W, const float* __restrict__ bias,
    float* __restrict__ C, int No)
{
    __shared__ float As[16][132];
    __shared__ float Ws[16][128];
    const int tid = threadIdx.x;
    const int row0 = blockIdx.y * 128;
    const int col0 = blockIdx.x * 128;
    const int tn = tid & 15, tm = tid >> 4;
    float acc[2][2][4][4] = {};

    for (int k0 = 0; k0 < K; k0 += 16) {
        // ---- stage A tile (transposed into LDS) ----
#pragma unroll
        for (int it = 0; it < 2; ++it) {
            int s = tid + it * 256;
            int m = s >> 2, kq = s & 3;
            int grow = row0 + m;
            int gcol = k0 + kq * 4;
            float4 v;
            if (MODE == 0) {
                v = *(const float4*)(A + (size_t)grow * K + gcol);
            } else {
                int bb = grow >> 8, ii = grow & 255;
                if (gcol < K1) {
                    v = *(const float4*)(X1 + ((size_t)(bb * Nn + ii)) * K1 + gcol);
                } else {
                    int jj = midx[bb * Nn + ii];
                    if (jj >= 0) {
                        int K2 = K - K1;
                        v = *(const float4*)(X2 + ((size_t)(bb * Nn + jj)) * K2 + (gcol - K1));
                    } else {
                        v = make_float4(0.f, 0.f, 0.f, 0.f);
                    }
                }
            }
            As[kq * 4 + 0][m] = v.x; As[kq * 4 + 1][m] = v.y;
            As[kq * 4 + 2][m] = v.z; As[kq * 4 + 3][m] = v.w;
        }
        // ---- stage W tile ----
#pragma unroll
        for (int it = 0; it < 2; ++it) {
            int s = tid + it * 256;
            int kk = s >> 5, n4 = s & 31;
            float4 v = *(const float4*)(W + (size_t)(k0 + kk) * No + col0 + n4 * 4);
            *(float4*)&Ws[kk][n4 * 4] = v;
        }
        __syncthreads();
        // ---- compute ----
#pragma unroll
        for (int k = 0; k < 16; ++k) {
            float a[2][4], w[2][4];
            *(float4*)a[0] = *(const float4*)&As[k][tm * 4];
            *(float4*)a[1] = *(const float4*)&As[k][64 + tm * 4];
            *(float4*)w[0] = *(const float4*)&Ws[k][tn * 4];
            *(float4*)w[1] = *(const float4*)&Ws[k][64 + tn * 4];
#pragma unroll
            for (int rq = 0; rq < 2; ++rq)
#pragma unroll
                for (int cq = 0; cq < 2; ++cq)
#pragma unroll
                    for (int r = 0; r < 4; ++r)
#pragma unroll
                        for (int c = 0; c < 4; ++c)
                            acc[rq][cq][r][c] += a[rq][r] * w[cq][c];
        }
        __syncthreads();
    }
    // ---- epilogue: bias (+relu) + store ----
#pragma unroll
    for (int rq = 0; rq < 2; ++rq)
#pragma unroll
        for (int cq = 0; cq < 2; ++cq) {
            int colb = col0 + cq * 64 + tn * 4;
            float4 bv = *(const float4*)(bias + colb);
#pragma unroll
            for (int r = 0; r < 4; ++r) {
                int grow = row0 + rq * 64 + tm * 4 + r;
                float4 o;
                o.x = acc[rq][cq][r][0] + bv.x;
                o.y = acc[rq][cq][r][1] + bv.y;
                o.z = acc[rq][cq][r][2] + bv.z;
                o.w = acc[rq][cq][r][3] + bv.w;
                if (RELU) {
                    o.x = fmaxf(o.x, 0.f); o.y = fmaxf(o.y, 0.f);
                    o.z = fmaxf(o.z, 0.f); o.w = fmaxf(o.w, 0.f);
                }
                *(float4*)(C + (size_t)grow * No + colb) = o;
            }
        }
}

// ---------------------------------------------------------------------------
// LayerNorm over D=1024. One block per row, 256 threads (4 elems/thread).
// Writes to out[row*ostride + ooff + d].
// ---------------------------------------------------------------------------
__global__ __launch_bounds__(256) void ln_k(
    const float* __restrict__ X, const float* __restrict__ g,
    const float* __restrict__ be, float* __restrict__ out,
    int ostride, int ooff)
{
    const int row = blockIdx.x;
    const int tid = threadIdx.x;
    float4 v = *(const float4*)(X + (size_t)row * VDIM + tid * 4);
    float s = v.x + v.y + v.z + v.w;
    __shared__ float lds[4];
    for (int o = 32; o; o >>= 1) s += __shfl_down(s, o, 64);
    if ((tid & 63) == 0) lds[tid >> 6] = s;
    __syncthreads();
    float mean = (lds[0] + lds[1] + lds[2] + lds[3]) * (1.f / VDIM);
    __syncthreads();
    float dx = v.x - mean, dy = v.y - mean, dz = v.z - mean, dw = v.w - mean;
    float q = dx * dx + dy * dy + dz * dz + dw * dw;
    for (int o = 32; o; o >>= 1) q += __shfl_down(q, o, 64);
    if ((tid & 63) == 0) lds[tid >> 6] = q;
    __syncthreads();
    float var = (lds[0] + lds[1] + lds[2] + lds[3]) * (1.f / VDIM);
    float rstd = rsqrtf(var + LNEPS);
    float4 gv = *(const float4*)(g + tid * 4);
    float4 bv = *(const float4*)(be + tid * 4);
    float4 o;
    o.x = dx * rstd * gv.x + bv.x;
    o.y = dy * rstd * gv.y + bv.y;
    o.z = dz * rstd * gv.z + bv.z;
    o.w = dw * rstd * gv.w + bv.w;
    *(float4*)(out + (size_t)row * ostride + ooff + tid * 4) = o;
}

// ---------------------------------------------------------------------------
extern "C" void kernel_launch(void* const* d_in, const int* in_sizes, int n_in,
                              void* d_out, int out_size, void* d_ws, size_t ws_size,
                              hipStream_t stream)
{
    const float* image   = (const float*)d_in[0];
    const float* pcf     = (const float*)d_in[1];
    const float* pimage  = (const float*)d_in[2];
    const float* ppcf    = (const float*)d_in[3];
    const float* psp     = (const float*)d_in[4];
    const int*   mask    = (const int*)d_in[5];
    const float* iw1 = (const float*)d_in[6];  const float* ib1 = (const float*)d_in[7];
    const float* iw2 = (const float*)d_in[8];  const float* ib2 = (const float*)d_in[9];
    const float* iw3 = (const float*)d_in[10]; const float* ib3 = (const float*)d_in[11];
    const float* ig  = (const float*)d_in[12]; const float* ibeta = (const float*)d_in[13];
    const float* pw1 = (const float*)d_in[14]; const float* pb1 = (const float*)d_in[15];
    const float* pw2 = (const float*)d_in[16]; const float* pb2 = (const float*)d_in[17];
    const float* pw3 = (const float*)d_in[18]; const float* pb3 = (const float*)d_in[19];
    const float* pg  = (const float*)d_in[20]; const float* pbeta = (const float*)d_in[21];
    const float* fw1 = (const float*)d_in[22]; const float* fb1 = (const float*)d_in[23];
    const float* fw2 = (const float*)d_in[24]; const float* fb2 = (const float*)d_in[25];
    const float* fg  = (const float*)d_in[26]; const float* fbeta = (const float*)d_in[27];

    float* out_vis = (float*)d_out;                       // [8192][1024]
    float* out_sp  = (float*)d_out + (size_t)Mrows * VDIM; // [8192][8]

    // workspace layout (floats). total ~52.5M floats ~= 210 MB
    float* ws   = (float*)d_ws;
    float* nf   = ws;                  // 8192
    float* np_  = ws + 8192;           // 8192
    int*   midx = (int*)(ws + 16384);  // 8192
    float* sim  = ws + 24576;          // 32*256*256 = 2,097,152
    float* bufA = sim + (size_t)Bn * Nn * Nn;          // 16,777,216 (64MB)
    float* bufB = bufA + (size_t)Mrows * 2048;         // 16,777,216 (64MB)
    float* bufD = bufB + (size_t)Mrows * 2048;         // 16,777,216 (64MB) vis_in

    // 1. row norms (current + prev)
    rownorm_k<<<dim3(Mrows, 2), 256, 0, stream>>>(image, pcf, pimage, ppcf, nf, np_);

    // 2. similarity matrix
    sim_k<<<dim3(4, 4, Bn), 256, 0, stream>>>(image, pcf, pimage, ppcf, nf, np_, sim);

    // 3. greedy match (also writes new_prev_spatial output)
    match_k<<<dim3(Bn), 256, 0, stream>>>(sim, mask, psp, midx, out_sp);

    // 4. img branch: h1 = relu(concat(image, gather(prev_img)) @ iw1 + ib1)
    gemm_k<1, 1><<<dim3(2048 / 128, Mrows / 128), 256, 0, stream>>>(
        nullptr, image, pimage, midx, 2 * IDIM, IDIM, iw1, ib1, bufA, 2048);
    // 5. h2 = h1 @ iw2 + ib2
    gemm_k<0, 0><<<dim3(2048 / 128, Mrows / 128), 256, 0, stream>>>(
        bufA, nullptr, nullptr, nullptr, 2048, 0, iw2, ib2, bufB, 2048);
    // 6. img3 = h2 @ iw3 + ib3  -> bufA (reuse)
    gemm_k<0, 0><<<dim3(VDIM / 128, Mrows / 128), 256, 0, stream>>>(
        bufB, nullptr, nullptr, nullptr, 2048, 0, iw3, ib3, bufA, VDIM);
    // 7. LN -> vis_in[:, 0:1024]
    ln_k<<<dim3(Mrows), 256, 0, stream>>>(bufA, ig, ibeta, bufD, 2048, 0);

    // 8. pc branch
    gemm_k<1, 1><<<dim3(PDIM / 128, Mrows / 128), 256, 0, stream>>>(
        nullptr, pcf, ppcf, midx, 2 * PDIM, PDIM, pw1, pb1, bufB, PDIM);
    gemm_k<0, 0><<<dim3(PDIM / 128, Mrows / 128), 256, 0, stream>>>(
        bufB, nullptr, nullptr, nullptr, PDIM, 0, pw2, pb2, bufA, PDIM);
    gemm_k<0, 0><<<dim3(VDIM / 128, Mrows / 128), 256, 0, stream>>>(
        bufA, nullptr, nullptr, nullptr, PDIM, 0, pw3, pb3, bufB, VDIM);
    ln_k<<<dim3(Mrows), 256, 0, stream>>>(bufB, pg, pbeta, bufD, 2048, 1024);

    // 9. fused branch: fh1 = relu(vis_in @ fw1 + fb1)
    gemm_k<0, 1><<<dim3(VDIM / 128, Mrows / 128), 256, 0, stream>>>(
        bufD, nullptr, nullptr, nullptr, 2048, 0, fw1, fb1, bufA, VDIM);
    // fh2 = fh1 @ fw2 + fb2
    gemm_k<0, 0><<<dim3(VDIM / 128, Mrows / 128), 256, 0, stream>>>(
        bufA, nullptr, nullptr, nullptr, VDIM, 0, fw2, fb2, bufB, VDIM);
    // final LN -> d_out
    ln_k<<<dim3(Mrows), 256, 0, stream>>>(bufB, fg, fbeta, out_vis, VDIM, 0);
}

// Round 2
// 1089.626 us; speedup vs baseline: 4.1691x; 4.1691x over previous
//
#include <hip/hip_runtime.h>
#include <math.h>

#define Bn 32
#define Nn 256
#define IDIM 2048
#define PDIM 768
#define VDIM 1024
#define SDIM 8
#define D2 2816
#define Mrows 8192
#define EPSN 1e-8f
#define LNEPS 1e-5f
#define THRESH 0.5f

typedef unsigned short u16;
typedef __attribute__((ext_vector_type(8))) short bf16x8;
typedef __attribute__((ext_vector_type(4))) float f32x4;

// fp32 -> bf16 round-to-nearest-even
__device__ __forceinline__ u16 f2b(float f) {
    unsigned u = __float_as_uint(f);
    unsigned r = (u + 0x7FFFu + ((u >> 16) & 1u)) >> 16;
    return (u16)r;
}

// async global->LDS, 16B per lane. LDS dest is wave-uniform base (+lane*16 by HW).
__device__ __forceinline__ void gload16(const void* g, void* l) {
    __builtin_amdgcn_global_load_lds(
        (const __attribute__((address_space(1))) unsigned*)g,
        (__attribute__((address_space(3))) unsigned*)l, 16, 0, 0);
}

// ---------------------------------------------------------------------------
// pack: fp32 image/pc -> bf16 concat rows [8192][2816], plus row L2 norms.
// grid (8192, 2): y=0 current -> featb/nf, y=1 prev -> pfeatb/np
// ---------------------------------------------------------------------------
__global__ __launch_bounds__(256) void pack_k(
    const float* __restrict__ img, const float* __restrict__ pc,
    const float* __restrict__ pimg, const float* __restrict__ ppc,
    u16* __restrict__ featb, u16* __restrict__ pfeatb,
    float* __restrict__ nf, float* __restrict__ np_)
{
    const int row = blockIdx.x, t = threadIdx.x;
    const float* I = blockIdx.y ? pimg : img;
    const float* P = blockIdx.y ? ppc : pc;
    u16* O = blockIdx.y ? pfeatb : featb;
    float s = 0.f;
    const float4* I4 = (const float4*)(I + (size_t)row * IDIM);
    float4 a = I4[t * 2], b = I4[t * 2 + 1];
    s += a.x * a.x + a.y * a.y + a.z * a.z + a.w * a.w;
    s += b.x * b.x + b.y * b.y + b.z * b.z + b.w * b.w;
    u16* op = O + (size_t)row * D2 + t * 8;
    *(ushort4*)op       = make_ushort4(f2b(a.x), f2b(a.y), f2b(a.z), f2b(a.w));
    *(ushort4*)(op + 4) = make_ushort4(f2b(b.x), f2b(b.y), f2b(b.z), f2b(b.w));
    if (t < 192) {
        float4 c = ((const float4*)(P + (size_t)row * PDIM))[t];
        s += c.x * c.x + c.y * c.y + c.z * c.z + c.w * c.w;
        *(ushort4*)(O + (size_t)row * D2 + IDIM + t * 4) =
            make_ushort4(f2b(c.x), f2b(c.y), f2b(c.z), f2b(c.w));
    }
    for (int o = 32; o; o >>= 1) s += __shfl_down(s, o, 64);
    __shared__ float l4[4];
    if ((t & 63) == 0) l4[t >> 6] = s;
    __syncthreads();
    if (t == 0) (blockIdx.y ? np_ : nf)[row] = sqrtf(l4[0] + l4[1] + l4[2] + l4[3]);
}

// ---------------------------------------------------------------------------
// weight transpose + bf16: W[K][No] fp32 -> Wt[No][K] bf16. 32x32 tiles.
// ---------------------------------------------------------------------------
__global__ __launch_bounds__(256) void twt_k(
    const float* __restrict__ W, u16* __restrict__ Wt, int K, int No)
{
    __shared__ float tb[32][33];
    const int tx = threadIdx.x & 31;
    const int ty = threadIdx.x >> 5; // 0..7
    const int n0 = blockIdx.x * 32, k0 = blockIdx.y * 32;
#pragma unroll
    for (int qq = 0; qq < 4; ++qq)
        tb[ty + 8 * qq][tx] = W[(size_t)(k0 + ty + 8 * qq) * No + n0 + tx];
    __syncthreads();
#pragma unroll
    for (int qq = 0; qq < 4; ++qq)
        Wt[(size_t)(n0 + ty + 8 * qq) * K + k0 + tx] = f2b(tb[tx][ty + 8 * qq]);
}

// ---------------------------------------------------------------------------
// MFMA GEMM, 128x128 tile, BK=32, 4 waves, each wave 64x64 (4x4 of 16x16x32).
// MODE 0: A = [M][K] bf16 plain (lda=K).
// MODE 1: A = concat(Acur[.,coff:coff+K1], gather(Aprev,midx)[.,coff:coff+K-K1])
//         both with row stride lda; midx<0 rows read zeros from zbuf.
// OUT 0: bf16 out (+bias, opt relu). OUT 1: fp32 out (+bias). OUT 2: sim
//         (per-batch B, scale by 1/(max(nf,eps)*max(np,eps)), fp32 out).
// LDS layout: per tile-row r (64B = 4 x 16B k-group slots), slot q holds
// k-group q ^ ((r>>1)&3)  (inverse-swizzle applied on global source addrs;
// swizzle applied on ds_read addrs -> <=2-way bank conflicts).
// ---------------------------------------------------------------------------
template <int MODE, int RELU, int OUT>
__global__ __launch_bounds__(256) void mm_k(
    const u16* __restrict__ A, const u16* __restrict__ Aprev,
    const int* __restrict__ midx, const float* __restrict__ zbuf,
    int lda, int coff, int K1,
    const u16* __restrict__ Bt, int K,
    const float* __restrict__ bias,
    const float* __restrict__ nf, const float* __restrict__ np_,
    void* __restrict__ Cout, int ldc)
{
    __shared__ __align__(16) u16 Asm[4096];
    __shared__ __align__(16) u16 Bsm[4096];
    const int tid = threadIdx.x;
    const int wave = tid >> 6, lane = tid & 63;
    const int row0 = blockIdx.y * 128;
    const int cC0 = blockIdx.x * 128;
    const int brow0 = (OUT == 2 ? (row0 >> 8) * Nn : 0) + cC0;

    // per-lane staging sources (2 chunks of 16 rows each per wave)
    const int la = lane >> 2, q = lane & 3;
    const u16* pA0[2]; const u16* pAp[2]; const u16* pZ[2]; const u16* pB0[2];
    bool zr[2];
    char* dstA[2]; char* dstB[2];
#pragma unroll
    for (int i = 0; i < 2; ++i) {
        int c = wave * 2 + i;
        int r = c * 16 + la;                 // tile row (A) / tile col (B)
        int sp = q ^ ((r >> 1) & 3);         // permuted 16B slot
        int grow = row0 + r;
        if (MODE == 0) {
            pA0[i] = A + (size_t)grow * lda + sp * 8;
            pAp[i] = nullptr; pZ[i] = nullptr; zr[i] = false;
        } else {
            pA0[i] = A + (size_t)grow * lda + coff + sp * 8;
            int jj = midx[grow];
            zr[i] = (jj < 0);
            pAp[i] = Aprev + (size_t)((grow & ~(Nn - 1)) + (jj < 0 ? 0 : jj)) * lda + coff + sp * 8;
            pZ[i] = (const u16*)zbuf + sp * 8;
        }
        pB0[i] = Bt + (size_t)(brow0 + r) * K + sp * 8;
        dstA[i] = (char*)Asm + c * 1024;
        dstB[i] = (char*)Bsm + c * 1024;
    }

    // fragment LDS read offsets (k-independent)
    const int wr = wave >> 1, wc = wave & 1;
    int aoff[4], boff[4];
#pragma unroll
    for (int m = 0; m < 4; ++m) {
        int r = wr * 64 + m * 16 + (lane & 15);
        aoff[m] = r * 64 + (((lane >> 4) ^ ((r >> 1) & 3)) << 4);
    }
#pragma unroll
    for (int n = 0; n < 4; ++n) {
        int c = wc * 64 + n * 16 + (lane & 15);
        boff[n] = c * 64 + (((lane >> 4) ^ ((c >> 1) & 3)) << 4);
    }

    f32x4 acc[4][4] = {};

    for (int k0 = 0; k0 < K; k0 += 32) {
#pragma unroll
        for (int i = 0; i < 2; ++i) {
            const u16* sa;
            if (MODE == 0) sa = pA0[i] + k0;
            else sa = (k0 < K1) ? (pA0[i] + k0)
                                : (zr[i] ? pZ[i] : (pAp[i] + (k0 - K1)));
            gload16(sa, dstA[i]);
            gload16(pB0[i] + k0, dstB[i]);
        }
        __syncthreads();
        bf16x8 av[4], bv[4];
#pragma unroll
        for (int m = 0; m < 4; ++m) av[m] = *(const bf16x8*)((const char*)Asm + aoff[m]);
#pragma unroll
        for (int n = 0; n < 4; ++n) bv[n] = *(const bf16x8*)((const char*)Bsm + boff[n]);
#pragma unroll
        for (int m = 0; m < 4; ++m)
#pragma unroll
            for (int n = 0; n < 4; ++n)
                acc[m][n] = __builtin_amdgcn_mfma_f32_16x16x32_bf16(av[m], bv[n], acc[m][n], 0, 0, 0);
        __syncthreads();
    }

    // epilogue
    const int rb = row0 + wr * 64;
    const int cl = cC0 + wc * 64 + (lane & 15); // C col for n=0
    float bs[4], sj[4];
    if (OUT < 2) {
#pragma unroll
        for (int n = 0; n < 4; ++n) bs[n] = bias[cl + n * 16];
    } else {
#pragma unroll
        for (int n = 0; n < 4; ++n) {
            int bcol = brow0 + wc * 64 + n * 16 + (lane & 15);
            sj[n] = 1.f / fmaxf(np_[bcol], EPSN);
        }
    }
#pragma unroll
    for (int m = 0; m < 4; ++m) {
#pragma unroll
        for (int n = 0; n < 4; ++n) {
            f32x4 v = acc[m][n];
#pragma unroll
            for (int rg = 0; rg < 4; ++rg) {
                int rr = rb + m * 16 + ((lane >> 4) << 2) + rg;
                float x = v[rg];
                if (OUT < 2) x += bs[n];
                if (RELU) x = fmaxf(x, 0.f);
                if (OUT == 0) {
                    ((u16*)Cout)[(size_t)rr * ldc + cl + n * 16] = f2b(x);
                } else if (OUT == 1) {
                    ((float*)Cout)[(size_t)rr * ldc + cl + n * 16] = x;
                } else {
                    float si = 1.f / fmaxf(nf[rr], EPSN);
                    ((float*)Cout)[(size_t)rr * ldc + cl + n * 16] = x * si * sj[n];
                }
            }
        }
    }
}

// ---------------------------------------------------------------------------
// Greedy match. One block per batch. Also zeroes zbuf (block 0) for GEMM use.
// ---------------------------------------------------------------------------
__global__ __launch_bounds__(256) void match_k(
    const float* __restrict__ sim, const int* __restrict__ mask,
    const float* __restrict__ psp, int* __restrict__ midx,
    float* __restrict__ osp, float* __restrict__ zb)
{
    const int b = blockIdx.x;
    const int j = threadIdx.x;
    const int lane = j & 63, wid = j >> 6;
    __shared__ int vis[256];
    __shared__ unsigned long long wb[4];
    __shared__ float wv[4];
    __shared__ int wi[4];
    __shared__ int fidx_s;
    if (b == 0) zb[j] = 0.f;
    vis[j] = 0;
    __syncthreads();
    size_t rowoff = ((size_t)b * Nn) * Nn + j;
    float s = sim[rowoff];
    int mk = mask[rowoff];
    for (int i = 0; i < Nn; ++i) {
        float scur = s; int mkcur = mk;
        bool valid = mkcur && (!vis[j]) && (scur >= THRESH);
        if (i + 1 < Nn) {  // prefetch next row
            s = sim[rowoff + (size_t)(i + 1) * Nn];
            mk = mask[rowoff + (size_t)(i + 1) * Nn];
        }
        unsigned long long bal = __ballot(valid);
        if (lane == 0) wb[wid] = bal;
        __syncthreads();
        bool found = (wb[0] | wb[1] | wb[2] | wb[3]) != 0ULL;
        if (found) {
            float v = valid ? scur : -INFINITY;
            int idx = j;
            for (int o = 32; o; o >>= 1) {
                float v2 = __shfl_down(v, o, 64);
                int i2 = __shfl_down(idx, o, 64);
                if (v2 > v || (v2 == v && i2 < idx)) { v = v2; idx = i2; }
            }
            if (lane == 0) { wv[wid] = v; wi[wid] = idx; }
            __syncthreads();
            if (j == 0) {
                float bv = wv[0]; int bi = wi[0];
                for (int w = 1; w < 4; ++w)
                    if (wv[w] > bv || (wv[w] == bv && wi[w] < bi)) { bv = wv[w]; bi = wi[w]; }
                fidx_s = bi;
                vis[bi] = 1;
                midx[b * Nn + i] = bi;
            }
            __syncthreads();
            int fi = fidx_s;
            if (j < SDIM)
                osp[((size_t)b * Nn + i) * SDIM + j] = psp[((size_t)b * Nn + fi) * SDIM + j];
        } else {
            if (j == 0) midx[b * Nn + i] = -1;
            if (j < SDIM) osp[((size_t)b * Nn + i) * SDIM + j] = 0.f;
        }
        __syncthreads();
    }
}

// ---------------------------------------------------------------------------
// LayerNorm over D=1024 (fp32 in). OB=1: bf16 out, OB=0: fp32 out.
// ---------------------------------------------------------------------------
template <int OB>
__global__ __launch_bounds__(256) void ln_k(
    const float* __restrict__ X, const float* __restrict__ g,
    const float* __restrict__ be, void* __restrict__ out,
    int ostride, int ooff)
{
    const int row = blockIdx.x, t = threadIdx.x;
    float4 v = *(const float4*)(X + (size_t)row * VDIM + t * 4);
    float s = v.x + v.y + v.z + v.w;
    __shared__ float l4[4];
    for (int o = 32; o; o >>= 1) s += __shfl_down(s, o, 64);
    if ((t & 63) == 0) l4[t >> 6] = s;
    __syncthreads();
    float mean = (l4[0] + l4[1] + l4[2] + l4[3]) * (1.f / VDIM);
    __syncthreads();
    float dx = v.x - mean, dy = v.y - mean, dz = v.z - mean, dw = v.w - mean;
    float qv = dx * dx + dy * dy + dz * dz + dw * dw;
    for (int o = 32; o; o >>= 1) qv += __shfl_down(qv, o, 64);
    if ((t & 63) == 0) l4[t >> 6] = qv;
    __syncthreads();
    float var = (l4[0] + l4[1] + l4[2] + l4[3]) * (1.f / VDIM);
    float rstd = rsqrtf(var + LNEPS);
    float4 gv = *(const float4*)(g + t * 4);
    float4 bv = *(const float4*)(be + t * 4);
    float ox = dx * rstd * gv.x + bv.x;
    float oy = dy * rstd * gv.y + bv.y;
    float oz = dz * rstd * gv.z + bv.z;
    float ow = dw * rstd * gv.w + bv.w;
    if (OB) {
        *(ushort4*)((u16*)out + (size_t)row * ostride + ooff + t * 4) =
            make_ushort4(f2b(ox), f2b(oy), f2b(oz), f2b(ow));
    } else {
        *(float4*)((float*)out + (size_t)row * ostride + ooff + t * 4) =
            make_float4(ox, oy, oz, ow);
    }
}

// ---------------------------------------------------------------------------
extern "C" void kernel_launch(void* const* d_in, const int* in_sizes, int n_in,
                              void* d_out, int out_size, void* d_ws, size_t ws_size,
                              hipStream_t stream)
{
    const float* image  = (const float*)d_in[0];
    const float* pcf    = (const float*)d_in[1];
    const float* pimage = (const float*)d_in[2];
    const float* ppcf   = (const float*)d_in[3];
    const float* psp    = (const float*)d_in[4];
    const int*   mask   = (const int*)d_in[5];
    const float* iw1 = (const float*)d_in[6];  const float* ib1 = (const float*)d_in[7];
    const float* iw2 = (const float*)d_in[8];  const float* ib2 = (const float*)d_in[9];
    const float* iw3 = (const float*)d_in[10]; const float* ib3 = (const float*)d_in[11];
    const float* ig  = (const float*)d_in[12]; const float* ibeta = (const float*)d_in[13];
    const float* pw1 = (const float*)d_in[14]; const float* pb1 = (const float*)d_in[15];
    const float* pw2 = (const float*)d_in[16]; const float* pb2 = (const float*)d_in[17];
    const float* pw3 = (const float*)d_in[18]; const float* pb3 = (const float*)d_in[19];
    const float* pg  = (const float*)d_in[20]; const float* pbeta = (const float*)d_in[21];
    const float* fw1 = (const float*)d_in[22]; const float* fb1 = (const float*)d_in[23];
    const float* fw2 = (const float*)d_in[24]; const float* fb2 = (const float*)d_in[25];
    const float* fg  = (const float*)d_in[26]; const float* fbeta = (const float*)d_in[27];

    float* out_vis = (float*)d_out;                        // [8192][1024]
    float* out_sp  = (float*)d_out + (size_t)Mrows * VDIM; // [8192][8]

    // workspace carve (total = 209,813,504 B, same footprint as round 1)
    char* w = (char*)d_ws;
    float* nf   = (float*)w; w += 32768;
    float* np_  = (float*)w; w += 32768;
    int*   midx = (int*)w;   w += 32768;
    u16*   Wt   = (u16*)w;   w += 16777216;   // JIT weight region (max = iw1t)
    u16*   featb  = (u16*)w; w += 46137344;   // A region
    u16*   pfeatb = (u16*)w; w += 46137344;   // B region
    char*  Creg = w; w += 33554432;
    char*  Dreg = w; w += 33554432;
    char*  Ereg = w; w += 33554432;

    float* zbuf = nf;                       // zeroed by match_k (nf dead after sim)
    float* sim  = (float*)Ereg;             // [8192][256] fp32
    u16*   ph1b = (u16*)Creg;               // [8192][768] bf16
    u16*   ph2b = (u16*)(Creg + 12582912);  // [8192][768] bf16
    float* preLNpc = (float*)Ereg;          // [8192][1024] fp32 (sim dead)
    u16*   visb = (u16*)Dreg;               // [8192][2048] bf16
    u16*   h1b  = (u16*)Creg;               // [8192][2048] bf16
    u16*   h2b  = (u16*)featb;              // A reuse
    float* preLNimg = (float*)pfeatb;       // B reuse
    u16*   fh1b = (u16*)pfeatb;             // B reuse (after LNimg)
    float* preLNf = (float*)featb;          // A reuse

    // 1. pack inputs -> bf16 concat rows + row norms
    pack_k<<<dim3(Mrows, 2), 256, 0, stream>>>(image, pcf, pimage, ppcf,
                                               featb, pfeatb, nf, np_);
    // 2. similarity (bf16 MFMA, fp32 out, normalized)
    mm_k<0, 0, 2><<<dim3(2, 64), 256, 0, stream>>>(
        featb, nullptr, nullptr, nullptr, D2, 0, 0,
        pfeatb, D2, nullptr, nf, np_, sim, Nn);
    // 3. greedy match (+ zero zbuf)
    match_k<<<dim3(Bn), 256, 0, stream>>>(sim, mask, psp, midx, out_sp, zbuf);

    // 4. pc branch
    twt_k<<<dim3(PDIM / 32, (2 * PDIM) / 32), 256, 0, stream>>>(pw1, Wt, 2 * PDIM, PDIM);
    mm_k<1, 1, 0><<<dim3(PDIM / 128, 64), 256, 0, stream>>>(
        featb, pfeatb, midx, zbuf, D2, IDIM, PDIM,
        Wt, 2 * PDIM, pb1, nullptr, nullptr, ph1b, PDIM);
    twt_k<<<dim3(PDIM / 32, PDIM / 32), 256, 0, stream>>>(pw2, Wt, PDIM, PDIM);
    mm_k<0, 0, 0><<<dim3(PDIM / 128, 64), 256, 0, stream>>>(
        ph1b, nullptr, nullptr, nullptr, PDIM, 0, 0,
        Wt, PDIM, pb2, nullptr, nullptr, ph2b, PDIM);
    twt_k<<<dim3(VDIM / 32, PDIM / 32), 256, 0, stream>>>(pw3, Wt, PDIM, VDIM);
    mm_k<0, 0, 1><<<dim3(VDIM / 128, 64), 256, 0, stream>>>(
        ph2b, nullptr, nullptr, nullptr, PDIM, 0, 0,
        Wt, PDIM, pb3, nullptr, nullptr, preLNpc, VDIM);
    ln_k<1><<<dim3(Mrows), 256, 0, stream>>>(preLNpc, pg, pbeta, visb, 2048, 1024);

    // 5. img branch
    twt_k<<<dim3(IDIM / 32, (2 * IDIM) / 32), 256, 0, stream>>>(iw1, Wt, 2 * IDIM, IDIM);
    mm_k<1, 1, 0><<<dim3(IDIM / 128, 64), 256, 0, stream>>>(
        featb, pfeatb, midx, zbuf, D2, 0, IDIM,
        Wt, 2 * IDIM, ib1, nullptr, nullptr, h1b, IDIM);
    twt_k<<<dim3(IDIM / 32, IDIM / 32), 256, 0, stream>>>(iw2, Wt, IDIM, IDIM);
    mm_k<0, 0, 0><<<dim3(IDIM / 128, 64), 256, 0, stream>>>(
        h1b, nullptr, nullptr, nullptr, IDIM, 0, 0,
        Wt, IDIM, ib2, nullptr, nullptr, h2b, IDIM);
    twt_k<<<dim3(VDIM / 32, IDIM / 32), 256, 0, stream>>>(iw3, Wt, IDIM, VDIM);
    mm_k<0, 0, 1><<<dim3(VDIM / 128, 64), 256, 0, stream>>>(
        h2b, nullptr, nullptr, nullptr, IDIM, 0, 0,
        Wt, IDIM, ib3, nullptr, nullptr, preLNimg, VDIM);
    ln_k<1><<<dim3(Mrows), 256, 0, stream>>>(preLNimg, ig, ibeta, visb, 2048, 0);

    // 6. fused branch
    twt_k<<<dim3(VDIM / 32, 2048 / 32), 256, 0, stream>>>(fw1, Wt, 2048, VDIM);
    mm_k<0, 1, 0><<<dim3(VDIM / 128, 64), 256, 0, stream>>>(
        visb, nullptr, nullptr, nullptr, 2048, 0, 0,
        Wt, 2048, fb1, nullptr, nullptr, fh1b, VDIM);
    twt_k<<<dim3(VDIM / 32, VDIM / 32), 256, 0, stream>>>(fw2, Wt, VDIM, VDIM);
    mm_k<0, 0, 1><<<dim3(VDIM / 128, 64), 256, 0, stream>>>(
        fh1b, nullptr, nullptr, nullptr, VDIM, 0, 0,
        Wt, VDIM, fb2, nullptr, nullptr, preLNf, VDIM);
    ln_k<0><<<dim3(Mrows), 256, 0, stream>>>(preLNf, fg, fbeta, out_vis, VDIM, 0);
}

// Round 4
// 965.681 us; speedup vs baseline: 4.7043x; 1.1283x over previous
//
#include <hip/hip_runtime.h>
#include <math.h>

#define Bn 32
#define Nn 256
#define IDIM 2048
#define PDIM 768
#define VDIM 1024
#define SDIM 8
#define D2 2816
#define Mrows 8192
#define EPSN 1e-8f
#define LNEPS 1e-5f
#define THRESH 0.5f

typedef unsigned short u16;
typedef __attribute__((ext_vector_type(8))) short bf16x8;
typedef __attribute__((ext_vector_type(4))) float f32x4;

// fp32 -> bf16 round-to-nearest-even
__device__ __forceinline__ u16 f2b(float f) {
    unsigned u = __float_as_uint(f);
    unsigned r = (u + 0x7FFFu + ((u >> 16) & 1u)) >> 16;
    return (u16)r;
}

// async global->LDS, 16B per lane. LDS dest is wave-uniform base (+lane*16 by HW).
__device__ __forceinline__ void gload16(const void* g, void* l) {
    __builtin_amdgcn_global_load_lds(
        (const __attribute__((address_space(1))) unsigned*)g,
        (__attribute__((address_space(3))) unsigned*)l, 16, 0, 0);
}

#define VMWAIT4 asm volatile("s_waitcnt vmcnt(4)" ::: "memory")
#define VMWAIT2 asm volatile("s_waitcnt vmcnt(2)" ::: "memory")
#define VMWAIT0 asm volatile("s_waitcnt vmcnt(0)" ::: "memory")
#define BAR() do { __builtin_amdgcn_s_barrier(); __builtin_amdgcn_sched_barrier(0); } while (0)
#define PRIO1 __builtin_amdgcn_s_setprio(1)
#define PRIO0 __builtin_amdgcn_s_setprio(0)

// ---------------------------------------------------------------------------
// pack: fp32 image/pc -> bf16 concat rows [8192][2816], plus row L2 norms.
// ---------------------------------------------------------------------------
__global__ __launch_bounds__(256) void pack_k(
    const float* __restrict__ img, const float* __restrict__ pc,
    const float* __restrict__ pimg, const float* __restrict__ ppc,
    u16* __restrict__ featb, u16* __restrict__ pfeatb,
    float* __restrict__ nf, float* __restrict__ np_)
{
    const int row = blockIdx.x, t = threadIdx.x;
    const float* I = blockIdx.y ? pimg : img;
    const float* P = blockIdx.y ? ppc : pc;
    u16* O = blockIdx.y ? pfeatb : featb;
    float s = 0.f;
    const float4* I4 = (const float4*)(I + (size_t)row * IDIM);
    float4 a = I4[t * 2], b = I4[t * 2 + 1];
    s += a.x * a.x + a.y * a.y + a.z * a.z + a.w * a.w;
    s += b.x * b.x + b.y * b.y + b.z * b.z + b.w * b.w;
    u16* op = O + (size_t)row * D2 + t * 8;
    *(ushort4*)op       = make_ushort4(f2b(a.x), f2b(a.y), f2b(a.z), f2b(a.w));
    *(ushort4*)(op + 4) = make_ushort4(f2b(b.x), f2b(b.y), f2b(b.z), f2b(b.w));
    if (t < 192) {
        float4 c = ((const float4*)(P + (size_t)row * PDIM))[t];
        s += c.x * c.x + c.y * c.y + c.z * c.z + c.w * c.w;
        *(ushort4*)(O + (size_t)row * D2 + IDIM + t * 4) =
            make_ushort4(f2b(c.x), f2b(c.y), f2b(c.z), f2b(c.w));
    }
    for (int o = 32; o; o >>= 1) s += __shfl_down(s, o, 64);
    __shared__ float l4[4];
    if ((t & 63) == 0) l4[t >> 6] = s;
    __syncthreads();
    if (t == 0) (blockIdx.y ? np_ : nf)[row] = sqrtf(l4[0] + l4[1] + l4[2] + l4[3]);
}

// ---------------------------------------------------------------------------
// weight transpose + bf16: W[K][No] fp32 -> Wt[No][K] bf16. 32x32 tiles.
// ---------------------------------------------------------------------------
__global__ __launch_bounds__(256) void twt_k(
    const float* __restrict__ W, u16* __restrict__ Wt, int K, int No)
{
    __shared__ float tb[32][33];
    const int tx = threadIdx.x & 31;
    const int ty = threadIdx.x >> 5;
    const int n0 = blockIdx.x * 32, k0 = blockIdx.y * 32;
#pragma unroll
    for (int qq = 0; qq < 4; ++qq)
        tb[ty + 8 * qq][tx] = W[(size_t)(k0 + ty + 8 * qq) * No + n0 + tx];
    __syncthreads();
#pragma unroll
    for (int qq = 0; qq < 4; ++qq)
        Wt[(size_t)(n0 + ty + 8 * qq) * K + k0 + tx] = f2b(tb[tx][ty + 8 * qq]);
}

// ---------------------------------------------------------------------------
// mm_k (round-2 structure, byte-offset reads) retained ONLY for sim (OUT=2).
// ---------------------------------------------------------------------------
template <int MODE, int RELU, int OUT>
__global__ __launch_bounds__(256) void mm_k(
    const u16* __restrict__ A, const u16* __restrict__ Aprev,
    const int* __restrict__ midx, const float* __restrict__ zbuf,
    int lda, int coff, int K1,
    const u16* __restrict__ Bt, int K,
    const float* __restrict__ bias,
    const float* __restrict__ nf, const float* __restrict__ np_,
    void* __restrict__ Cout, int ldc)
{
    __shared__ __align__(16) u16 Asm[4096];
    __shared__ __align__(16) u16 Bsm[4096];
    const int tid = threadIdx.x;
    const int wave = tid >> 6, lane = tid & 63;
    const int row0 = blockIdx.y * 128;
    const int cC0 = blockIdx.x * 128;
    const int brow0 = (OUT == 2 ? (row0 >> 8) * Nn : 0) + cC0;

    const int la = lane >> 2, q = lane & 3;
    const u16* pA0[2]; const u16* pB0[2];
    char* dstA[2]; char* dstB[2];
#pragma unroll
    for (int i = 0; i < 2; ++i) {
        int c = wave * 2 + i;
        int r = c * 16 + la;
        int sp = q ^ ((r >> 1) & 3);
        int grow = row0 + r;
        pA0[i] = A + (size_t)grow * lda + sp * 8;
        pB0[i] = Bt + (size_t)(brow0 + r) * K + sp * 8;
        dstA[i] = (char*)Asm + c * 1024;
        dstB[i] = (char*)Bsm + c * 1024;
    }

    const int wr = wave >> 1, wc = wave & 1;
    int aoff[4], boff[4];   // BYTE offsets into Asm/Bsm
#pragma unroll
    for (int m = 0; m < 4; ++m) {
        int r = wr * 64 + m * 16 + (lane & 15);
        aoff[m] = r * 64 + (((lane >> 4) ^ ((r >> 1) & 3)) << 4);
    }
#pragma unroll
    for (int n = 0; n < 4; ++n) {
        int c = wc * 64 + n * 16 + (lane & 15);
        boff[n] = c * 64 + (((lane >> 4) ^ ((c >> 1) & 3)) << 4);
    }

    f32x4 acc[4][4] = {};

    for (int k0 = 0; k0 < K; k0 += 32) {
#pragma unroll
        for (int i = 0; i < 2; ++i) {
            gload16(pA0[i] + k0, dstA[i]);
            gload16(pB0[i] + k0, dstB[i]);
        }
        __syncthreads();
        bf16x8 av[4], bv[4];
#pragma unroll
        for (int m = 0; m < 4; ++m) av[m] = *(const bf16x8*)((const char*)Asm + aoff[m]);
#pragma unroll
        for (int n = 0; n < 4; ++n) bv[n] = *(const bf16x8*)((const char*)Bsm + boff[n]);
#pragma unroll
        for (int m = 0; m < 4; ++m)
#pragma unroll
            for (int n = 0; n < 4; ++n)
                acc[m][n] = __builtin_amdgcn_mfma_f32_16x16x32_bf16(av[m], bv[n], acc[m][n], 0, 0, 0);
        __syncthreads();
    }

    const int rb = row0 + wr * 64;
    const int cl = cC0 + wc * 64 + (lane & 15);
    float sj[4];
#pragma unroll
    for (int n = 0; n < 4; ++n) {
        int bcol = brow0 + wc * 64 + n * 16 + (lane & 15);
        sj[n] = 1.f / fmaxf(np_[bcol], EPSN);
    }
#pragma unroll
    for (int m = 0; m < 4; ++m) {
#pragma unroll
        for (int n = 0; n < 4; ++n) {
            f32x4 v = acc[m][n];
#pragma unroll
            for (int rg = 0; rg < 4; ++rg) {
                int rr = rb + m * 16 + ((lane >> 4) << 2) + rg;
                float si = 1.f / fmaxf(nf[rr], EPSN);
                ((float*)Cout)[(size_t)rr * ldc + cl + n * 16] = v[rg] * si * sj[n];
            }
        }
    }
}

// ---------------------------------------------------------------------------
// mm8_k: 256x256 8-phase MFMA GEMM (BK=64, 8 waves, dbuf LDS, counted vmcnt,
// XOR slot swizzle c = s^(r&7), setprio around MFMA, XCD-bijective swizzle).
// Strided wave mapping: A-frag m -> tile row m*32+wr*16; B-frag n -> col
// n*64+wc*16, so quadrant (mh,nh) consumes exactly A-half mh + B-half nh.
// OUT: 0 bf16+bias, 1 fp32+bias.
// ---------------------------------------------------------------------------
template <int MODE, int RELU, int OUT>
__global__ __launch_bounds__(512, 2) void mm8_k(
    const u16* __restrict__ A, const u16* __restrict__ Aprev,
    const int* __restrict__ midx, const u16* __restrict__ zb,
    int lda, int coff, int K1,
    const u16* __restrict__ Bt, int K,
    const float* __restrict__ bias,
    void* __restrict__ Cout, int ldc, int nblk)
{
    __shared__ __align__(16) u16 smem[65536];   // 128 KiB: A(2x32K) | B(2x32K)
    char* ldsv = (char*)smem;

    const int tid = threadIdx.x;
    const int wave = tid >> 6, lane = tid & 63;
    const int l15 = lane & 15, l4 = lane >> 4;
    const int wr = wave >> 2, wc = wave & 3;

    // XCD-bijective block swizzle (m204): chunk grid across 8 XCDs.
    const int nwg = nblk * 32;
    const int orig = blockIdx.x;
    const int xcd = orig & 7, lid = orig >> 3;
    const int qq = nwg >> 3, rr8 = nwg & 7;
    const int swz = (xcd < rr8 ? xcd * (qq + 1) : rr8 * (qq + 1) + (xcd - rr8) * qq) + lid;
    const int row0 = (swz & 31) * 256;
    const int col0 = (swz >> 5) * 256;

    // ---- staging source pointers: (h,i) -> row r = h*128 + ((i*512+tid)>>3),
    // slot s = tid&7 holds global chunk c = s ^ (r&7).
    const u16* pA[2][2]; const u16* pA2[2][2]; const u16* pB[2][2];
    int cA8[2][2]; bool okA[2][2];
#pragma unroll
    for (int h = 0; h < 2; ++h)
#pragma unroll
        for (int i = 0; i < 2; ++i) {
            int lrow = (i * 512 + tid) >> 3;
            int r = h * 128 + lrow;
            int c = (tid & 7) ^ (lrow & 7);
            cA8[h][i] = c * 8;
            int grow = row0 + r;
            if (MODE == 0) {
                pA[h][i] = A + (size_t)grow * lda + c * 8;
                pA2[h][i] = nullptr; okA[h][i] = true;
            } else {
                pA[h][i] = A + (size_t)grow * lda + coff + c * 8;
                int jj = midx[grow];
                okA[h][i] = (jj >= 0);
                pA2[h][i] = okA[h][i]
                    ? (Aprev + (size_t)((grow & ~(Nn - 1)) + jj) * lda + coff + c * 8 - K1)
                    : (zb + c * 8);
            }
            pB[h][i] = Bt + (size_t)(col0 + r) * K + c * 8;
        }

#define STAGEA(h, kt, pp) do {                                                   \
    _Pragma("unroll")                                                            \
    for (int i_ = 0; i_ < 2; ++i_) {                                             \
        const u16* s_;                                                           \
        if (MODE == 0) s_ = pA[h][i_] + (kt);                                    \
        else {                                                                   \
            int gc_ = (kt) + cA8[h][i_];                                         \
            s_ = (gc_ < K1) ? (pA[h][i_] + (kt))                                 \
                            : (okA[h][i_] ? pA2[h][i_] + (kt) : pA2[h][i_]);     \
        }                                                                        \
        gload16(s_, ldsv + ((pp) * 32768 + (h) * 16384 + i_ * 8192 + wave * 1024)); \
    }                                                                            \
} while (0)

#define STAGEB(h, kt, pp) do {                                                   \
    _Pragma("unroll")                                                            \
    for (int i_ = 0; i_ < 2; ++i_)                                               \
        gload16(pB[h][i_] + (kt),                                                \
                ldsv + (65536 + (pp) * 32768 + (h) * 16384 + i_ * 8192 + wave * 1024)); \
} while (0)

    // ---- ds_read byte offsets (within one A/B buffer)
    int aoffs[8][2], boffs[4][2];
#pragma unroll
    for (int m = 0; m < 8; ++m) {
        int r = m * 32 + wr * 16 + l15;
#pragma unroll
        for (int ks = 0; ks < 2; ++ks)
            aoffs[m][ks] = r * 128 + (((ks * 4 + l4) ^ (lane & 7)) << 4);
    }
#pragma unroll
    for (int n = 0; n < 4; ++n) {
        int r = n * 64 + wc * 16 + l15;
#pragma unroll
        for (int ks = 0; ks < 2; ++ks)
            boffs[n][ks] = r * 128 + (((ks * 4 + l4) ^ (lane & 7)) << 4);
    }

    bf16x8 avc[4][2], bvc[2][2];
    f32x4 acc[8][4] = {};

#define READA(mh, base) do {                                                     \
    _Pragma("unroll")                                                            \
    for (int m_ = 0; m_ < 4; ++m_) {                                             \
        avc[m_][0] = *(const bf16x8*)((base) + aoffs[(mh) * 4 + m_][0]);         \
        avc[m_][1] = *(const bf16x8*)((base) + aoffs[(mh) * 4 + m_][1]);         \
    }                                                                            \
} while (0)

#define READB(nh, base) do {                                                     \
    _Pragma("unroll")                                                            \
    for (int n_ = 0; n_ < 2; ++n_) {                                             \
        bvc[n_][0] = *(const bf16x8*)((base) + boffs[(nh) * 2 + n_][0]);         \
        bvc[n_][1] = *(const bf16x8*)((base) + boffs[(nh) * 2 + n_][1]);         \
    }                                                                            \
} while (0)

#define MFMA16(mh, nh) do {                                                      \
    _Pragma("unroll")                                                            \
    for (int ks_ = 0; ks_ < 2; ++ks_)                                            \
    _Pragma("unroll")                                                            \
    for (int m_ = 0; m_ < 4; ++m_)                                               \
    _Pragma("unroll")                                                            \
    for (int n_ = 0; n_ < 2; ++n_)                                               \
        acc[(mh) * 4 + m_][(nh) * 2 + n_] = __builtin_amdgcn_mfma_f32_16x16x32_bf16( \
            avc[m_][ks_], bvc[n_][ks_], acc[(mh) * 4 + m_][(nh) * 2 + n_], 0, 0, 0); \
} while (0)

    const int nt = K >> 6;

    // prologue: stage tile 0 into p=0, issue order [A0,B0,A1,B1]
    STAGEA(0, 0, 0); STAGEB(0, 0, 0); STAGEA(1, 0, 0); STAGEB(1, 0, 0);

    int t = 0;
    for (; t < nt - 1; ++t) {
        const int p = t & 1;
        const char* bA = ldsv + p * 32768;
        const char* bB = ldsv + 65536 + p * 32768;
        const int kn = (t + 1) << 6;
        // q1: needs A0,B0 of tile t  (8 in flight -> wait 4 -> A0,B0 retired)
        VMWAIT4; BAR();
        STAGEA(0, kn, p ^ 1);
        READA(0, bA); READB(0, bB);
        PRIO1; MFMA16(0, 0); PRIO0;
        // q2: needs A1 (6 in flight -> wait 4 -> A1 retired)
        VMWAIT4; BAR();
        STAGEB(0, kn, p ^ 1);
        READA(1, bA);
        PRIO1; MFMA16(1, 0); PRIO0;
        // q3: needs B1 (6 in flight -> wait 4 -> B1 retired)
        VMWAIT4; BAR();
        STAGEA(1, kn, p ^ 1);
        READB(1, bB);
        PRIO1; MFMA16(1, 1); PRIO0;
        // q4: nothing new to wait for
        BAR();
        STAGEB(1, kn, p ^ 1);
        READA(0, bA);
        PRIO1; MFMA16(0, 1); PRIO0;
    }
    // last tile: drain 4/2/0
    {
        const int p = t & 1;
        const char* bA = ldsv + p * 32768;
        const char* bB = ldsv + 65536 + p * 32768;
        VMWAIT4; BAR(); READA(0, bA); READB(0, bB); PRIO1; MFMA16(0, 0); PRIO0;
        VMWAIT2; BAR(); READA(1, bA);               PRIO1; MFMA16(1, 0); PRIO0;
        VMWAIT0; BAR(); READB(1, bB);               PRIO1; MFMA16(1, 1); PRIO0;
        BAR();          READA(0, bA);               PRIO1; MFMA16(0, 1); PRIO0;
    }

    // epilogue
#pragma unroll
    for (int n = 0; n < 4; ++n) {
        const int col = col0 + n * 64 + wc * 16 + l15;
        const float bz = bias[col];
#pragma unroll
        for (int m = 0; m < 8; ++m) {
#pragma unroll
            for (int rg = 0; rg < 4; ++rg) {
                int row = row0 + m * 32 + wr * 16 + l4 * 4 + rg;
                float x = acc[m][n][rg] + bz;
                if (RELU) x = fmaxf(x, 0.f);
                if (OUT == 0) ((u16*)Cout)[(size_t)row * ldc + col] = f2b(x);
                else          ((float*)Cout)[(size_t)row * ldc + col] = x;
            }
        }
    }
#undef STAGEA
#undef STAGEB
#undef READA
#undef READB
#undef MFMA16
}

// ---------------------------------------------------------------------------
// Greedy match. One block per batch. Also zeroes zbuf (block 0).
// ---------------------------------------------------------------------------
__global__ __launch_bounds__(256) void match_k(
    const float* __restrict__ sim, const int* __restrict__ mask,
    const float* __restrict__ psp, int* __restrict__ midx,
    float* __restrict__ osp, float* __restrict__ zb)
{
    const int b = blockIdx.x;
    const int j = threadIdx.x;
    const int lane = j & 63, wid = j >> 6;
    __shared__ int vis[256];
    __shared__ unsigned long long wb[4];
    __shared__ float wv[4];
    __shared__ int wi[4];
    __shared__ int fidx_s;
    if (b == 0) zb[j] = 0.f;
    vis[j] = 0;
    __syncthreads();
    size_t rowoff = ((size_t)b * Nn) * Nn + j;
    float s = sim[rowoff];
    int mk = mask[rowoff];
    for (int i = 0; i < Nn; ++i) {
        float scur = s; int mkcur = mk;
        bool valid = mkcur && (!vis[j]) && (scur >= THRESH);
        if (i + 1 < Nn) {
            s = sim[rowoff + (size_t)(i + 1) * Nn];
            mk = mask[rowoff + (size_t)(i + 1) * Nn];
        }
        unsigned long long bal = __ballot(valid);
        if (lane == 0) wb[wid] = bal;
        __syncthreads();
        bool found = (wb[0] | wb[1] | wb[2] | wb[3]) != 0ULL;
        if (found) {
            float v = valid ? scur : -INFINITY;
            int idx = j;
            for (int o = 32; o; o >>= 1) {
                float v2 = __shfl_down(v, o, 64);
                int i2 = __shfl_down(idx, o, 64);
                if (v2 > v || (v2 == v && i2 < idx)) { v = v2; idx = i2; }
            }
            if (lane == 0) { wv[wid] = v; wi[wid] = idx; }
            __syncthreads();
            if (j == 0) {
                float bv = wv[0]; int bi = wi[0];
                for (int w = 1; w < 4; ++w)
                    if (wv[w] > bv || (wv[w] == bv && wi[w] < bi)) { bv = wv[w]; bi = wi[w]; }
                fidx_s = bi;
                vis[bi] = 1;
                midx[b * Nn + i] = bi;
            }
            __syncthreads();
            int fi = fidx_s;
            if (j < SDIM)
                osp[((size_t)b * Nn + i) * SDIM + j] = psp[((size_t)b * Nn + fi) * SDIM + j];
        } else {
            if (j == 0) midx[b * Nn + i] = -1;
            if (j < SDIM) osp[((size_t)b * Nn + i) * SDIM + j] = 0.f;
        }
        __syncthreads();
    }
}

// ---------------------------------------------------------------------------
// LayerNorm over D=1024 (fp32 in). OB=1: bf16 out, OB=0: fp32 out.
// ---------------------------------------------------------------------------
template <int OB>
__global__ __launch_bounds__(256) void ln_k(
    const float* __restrict__ X, const float* __restrict__ g,
    const float* __restrict__ be, void* __restrict__ out,
    int ostride, int ooff)
{
    const int row = blockIdx.x, t = threadIdx.x;
    float4 v = *(const float4*)(X + (size_t)row * VDIM + t * 4);
    float s = v.x + v.y + v.z + v.w;
    __shared__ float l4[4];
    for (int o = 32; o; o >>= 1) s += __shfl_down(s, o, 64);
    if ((t & 63) == 0) l4[t >> 6] = s;
    __syncthreads();
    float mean = (l4[0] + l4[1] + l4[2] + l4[3]) * (1.f / VDIM);
    __syncthreads();
    float dx = v.x - mean, dy = v.y - mean, dz = v.z - mean, dw = v.w - mean;
    float qv = dx * dx + dy * dy + dz * dz + dw * dw;
    for (int o = 32; o; o >>= 1) qv += __shfl_down(qv, o, 64);
    if ((t & 63) == 0) l4[t >> 6] = qv;
    __syncthreads();
    float var = (l4[0] + l4[1] + l4[2] + l4[3]) * (1.f / VDIM);
    float rstd = rsqrtf(var + LNEPS);
    float4 gv = *(const float4*)(g + t * 4);
    float4 bv = *(const float4*)(be + t * 4);
    float ox = dx * rstd * gv.x + bv.x;
    float oy = dy * rstd * gv.y + bv.y;
    float oz = dz * rstd * gv.z + bv.z;
    float ow = dw * rstd * gv.w + bv.w;
    if (OB) {
        *(ushort4*)((u16*)out + (size_t)row * ostride + ooff + t * 4) =
            make_ushort4(f2b(ox), f2b(oy), f2b(oz), f2b(ow));
    } else {
        *(float4*)((float*)out + (size_t)row * ostride + ooff + t * 4) =
            make_float4(ox, oy, oz, ow);
    }
}

// ---------------------------------------------------------------------------
extern "C" void kernel_launch(void* const* d_in, const int* in_sizes, int n_in,
                              void* d_out, int out_size, void* d_ws, size_t ws_size,
                              hipStream_t stream)
{
    const float* image  = (const float*)d_in[0];
    const float* pcf    = (const float*)d_in[1];
    const float* pimage = (const float*)d_in[2];
    const float* ppcf   = (const float*)d_in[3];
    const float* psp    = (const float*)d_in[4];
    const int*   mask   = (const int*)d_in[5];
    const float* iw1 = (const float*)d_in[6];  const float* ib1 = (const float*)d_in[7];
    const float* iw2 = (const float*)d_in[8];  const float* ib2 = (const float*)d_in[9];
    const float* iw3 = (const float*)d_in[10]; const float* ib3 = (const float*)d_in[11];
    const float* ig  = (const float*)d_in[12]; const float* ibeta = (const float*)d_in[13];
    const float* pw1 = (const float*)d_in[14]; const float* pb1 = (const float*)d_in[15];
    const float* pw2 = (const float*)d_in[16]; const float* pb2 = (const float*)d_in[17];
    const float* pw3 = (const float*)d_in[18]; const float* pb3 = (const float*)d_in[19];
    const float* pg  = (const float*)d_in[20]; const float* pbeta = (const float*)d_in[21];
    const float* fw1 = (const float*)d_in[22]; const float* fb1 = (const float*)d_in[23];
    const float* fw2 = (const float*)d_in[24]; const float* fb2 = (const float*)d_in[25];
    const float* fg  = (const float*)d_in[26]; const float* fbeta = (const float*)d_in[27];

    float* out_vis = (float*)d_out;                        // [8192][1024]
    float* out_sp  = (float*)d_out + (size_t)Mrows * VDIM; // [8192][8]

    // workspace carve (same 209.8 MB footprint as round 2)
    char* w = (char*)d_ws;
    float* nf   = (float*)w; w += 32768;
    float* np_  = (float*)w; w += 32768;
    int*   midx = (int*)w;   w += 32768;
    u16*   Wt   = (u16*)w;   w += 16777216;   // JIT weight region (max = iw1t)
    u16*   featb  = (u16*)w; w += 46137344;   // A region
    u16*   pfeatb = (u16*)w; w += 46137344;   // B region
    char*  Creg = w; w += 33554432;
    char*  Dreg = w; w += 33554432;
    char*  Ereg = w; w += 33554432;

    float* zbuf = nf;                       // zeroed by match_k (nf dead after sim)
    float* sim  = (float*)Ereg;             // [8192][256] fp32
    u16*   ph1b = (u16*)Creg;               // [8192][768] bf16
    u16*   ph2b = (u16*)(Creg + 12582912);  // [8192][768] bf16
    float* preLNpc = (float*)Ereg;          // [8192][1024] fp32 (sim dead)
    u16*   visb = (u16*)Dreg;               // [8192][2048] bf16
    u16*   h1b  = (u16*)Creg;               // [8192][2048] bf16
    u16*   h2b  = (u16*)featb;              // A reuse
    float* preLNimg = (float*)pfeatb;       // B reuse
    u16*   fh1b = (u16*)pfeatb;             // B reuse (after LNimg)
    float* preLNf = (float*)featb;          // A reuse

    // 1. pack inputs -> bf16 concat rows + row norms
    pack_k<<<dim3(Mrows, 2), 256, 0, stream>>>(image, pcf, pimage, ppcf,
                                               featb, pfeatb, nf, np_);
    // 2. similarity (bf16 MFMA, fp32 out, normalized)
    mm_k<0, 0, 2><<<dim3(2, 64), 256, 0, stream>>>(
        featb, nullptr, nullptr, nullptr, D2, 0, 0,
        pfeatb, D2, nullptr, nf, np_, sim, Nn);
    // 3. greedy match (+ zero zbuf)
    match_k<<<dim3(Bn), 256, 0, stream>>>(sim, mask, psp, midx, out_sp, zbuf);

    // 4. pc branch
    twt_k<<<dim3(PDIM / 32, (2 * PDIM) / 32), 256, 0, stream>>>(pw1, Wt, 2 * PDIM, PDIM);
    mm8_k<1, 1, 0><<<dim3(3 * 32), 512, 0, stream>>>(
        featb, pfeatb, midx, (const u16*)zbuf, D2, IDIM, PDIM,
        Wt, 2 * PDIM, pb1, ph1b, PDIM, 3);
    twt_k<<<dim3(PDIM / 32, PDIM / 32), 256, 0, stream>>>(pw2, Wt, PDIM, PDIM);
    mm8_k<0, 0, 0><<<dim3(3 * 32), 512, 0, stream>>>(
        ph1b, nullptr, nullptr, nullptr, PDIM, 0, 0,
        Wt, PDIM, pb2, ph2b, PDIM, 3);
    twt_k<<<dim3(VDIM / 32, PDIM / 32), 256, 0, stream>>>(pw3, Wt, PDIM, VDIM);
    mm8_k<0, 0, 1><<<dim3(4 * 32), 512, 0, stream>>>(
        ph2b, nullptr, nullptr, nullptr, PDIM, 0, 0,
        Wt, PDIM, pb3, preLNpc, VDIM, 4);
    ln_k<1><<<dim3(Mrows), 256, 0, stream>>>(preLNpc, pg, pbeta, visb, 2048, 1024);

    // 5. img branch
    twt_k<<<dim3(IDIM / 32, (2 * IDIM) / 32), 256, 0, stream>>>(iw1, Wt, 2 * IDIM, IDIM);
    mm8_k<1, 1, 0><<<dim3(8 * 32), 512, 0, stream>>>(
        featb, pfeatb, midx, (const u16*)zbuf, D2, 0, IDIM,
        Wt, 2 * IDIM, ib1, h1b, IDIM, 8);
    twt_k<<<dim3(IDIM / 32, IDIM / 32), 256, 0, stream>>>(iw2, Wt, IDIM, IDIM);
    mm8_k<0, 0, 0><<<dim3(8 * 32), 512, 0, stream>>>(
        h1b, nullptr, nullptr, nullptr, IDIM, 0, 0,
        Wt, IDIM, ib2, h2b, IDIM, 8);
    twt_k<<<dim3(VDIM / 32, IDIM / 32), 256, 0, stream>>>(iw3, Wt, IDIM, VDIM);
    mm8_k<0, 0, 1><<<dim3(4 * 32), 512, 0, stream>>>(
        h2b, nullptr, nullptr, nullptr, IDIM, 0, 0,
        Wt, IDIM, ib3, preLNimg, VDIM, 4);
    ln_k<1><<<dim3(Mrows), 256, 0, stream>>>(preLNimg, ig, ibeta, visb, 2048, 0);

    // 6. fused branch
    twt_k<<<dim3(VDIM / 32, 2048 / 32), 256, 0, stream>>>(fw1, Wt, 2048, VDIM);
    mm8_k<0, 1, 0><<<dim3(4 * 32), 512, 0, stream>>>(
        visb, nullptr, nullptr, nullptr, 2048, 0, 0,
        Wt, 2048, fb1, fh1b, VDIM, 4);
    twt_k<<<dim3(VDIM / 32, VDIM / 32), 256, 0, stream>>>(fw2, Wt, VDIM, VDIM);
    mm8_k<0, 0, 1><<<dim3(4 * 32), 512, 0, stream>>>(
        fh1b, nullptr, nullptr, nullptr, VDIM, 0, 0,
        Wt, VDIM, fb2, preLNf, VDIM, 4);
    ln_k<0><<<dim3(Mrows), 256, 0, stream>>>(preLNf, fg, fbeta, out_vis, VDIM, 0);
}

// Round 5
// 819.184 us; speedup vs baseline: 5.5455x; 1.1788x over previous
//
#include <hip/hip_runtime.h>
#include <math.h>

#define Bn 32
#define Nn 256
#define IDIM 2048
#define PDIM 768
#define VDIM 1024
#define SDIM 8
#define D2 2816
#define Mrows 8192
#define EPSN 1e-8f
#define LNEPS 1e-5f
#define THRESH 0.5f

typedef unsigned short u16;
typedef unsigned long long u64;
typedef __attribute__((ext_vector_type(8))) short bf16x8;
typedef __attribute__((ext_vector_type(4))) float f32x4;

// fp32 -> bf16 round-to-nearest-even
__device__ __forceinline__ u16 f2b(float f) {
    unsigned u = __float_as_uint(f);
    unsigned r = (u + 0x7FFFu + ((u >> 16) & 1u)) >> 16;
    return (u16)r;
}

__device__ __forceinline__ void gload16(const void* g, void* l) {
    __builtin_amdgcn_global_load_lds(
        (const __attribute__((address_space(1))) unsigned*)g,
        (__attribute__((address_space(3))) unsigned*)l, 16, 0, 0);
}

#define VMWAIT4 asm volatile("s_waitcnt vmcnt(4)" ::: "memory")
#define VMWAIT2 asm volatile("s_waitcnt vmcnt(2)" ::: "memory")
#define VMWAIT0 asm volatile("s_waitcnt vmcnt(0)" ::: "memory")
#define BAR() do { __builtin_amdgcn_s_barrier(); __builtin_amdgcn_sched_barrier(0); } while (0)
#define PRIO1 __builtin_amdgcn_s_setprio(1)
#define PRIO0 __builtin_amdgcn_s_setprio(0)

// ---------------------------------------------------------------------------
// pack: fp32 image/pc -> bf16 concat rows [8192][2816], plus row L2 norms.
// ---------------------------------------------------------------------------
__global__ __launch_bounds__(256) void pack_k(
    const float* __restrict__ img, const float* __restrict__ pc,
    const float* __restrict__ pimg, const float* __restrict__ ppc,
    u16* __restrict__ featb, u16* __restrict__ pfeatb,
    float* __restrict__ nf, float* __restrict__ np_)
{
    const int row = blockIdx.x, t = threadIdx.x;
    const float* I = blockIdx.y ? pimg : img;
    const float* P = blockIdx.y ? ppc : pc;
    u16* O = blockIdx.y ? pfeatb : featb;
    float s = 0.f;
    const float4* I4 = (const float4*)(I + (size_t)row * IDIM);
    float4 a = I4[t * 2], b = I4[t * 2 + 1];
    s += a.x * a.x + a.y * a.y + a.z * a.z + a.w * a.w;
    s += b.x * b.x + b.y * b.y + b.z * b.z + b.w * b.w;
    u16* op = O + (size_t)row * D2 + t * 8;
    *(ushort4*)op       = make_ushort4(f2b(a.x), f2b(a.y), f2b(a.z), f2b(a.w));
    *(ushort4*)(op + 4) = make_ushort4(f2b(b.x), f2b(b.y), f2b(b.z), f2b(b.w));
    if (t < 192) {
        float4 c = ((const float4*)(P + (size_t)row * PDIM))[t];
        s += c.x * c.x + c.y * c.y + c.z * c.z + c.w * c.w;
        *(ushort4*)(O + (size_t)row * D2 + IDIM + t * 4) =
            make_ushort4(f2b(c.x), f2b(c.y), f2b(c.z), f2b(c.w));
    }
    for (int o = 32; o; o >>= 1) s += __shfl_down(s, o, 64);
    __shared__ float l4[4];
    if ((t & 63) == 0) l4[t >> 6] = s;
    __syncthreads();
    if (t == 0) (blockIdx.y ? np_ : nf)[row] = sqrtf(l4[0] + l4[1] + l4[2] + l4[3]);
}

// ---------------------------------------------------------------------------
// grouped weight transpose: 8 weights, W[K][No] fp32 -> Wt[No][K] bf16.
// ---------------------------------------------------------------------------
struct TD { const float* W; u16* Wt; int K, No, blk0; };

__global__ __launch_bounds__(256) void twtg_k(
    TD a0, TD a1, TD a2, TD a3, TD a4, TD a5, TD a6, TD a7)
{
    const int bid = blockIdx.x;
    TD d;
    if      (bid >= a7.blk0) d = a7;
    else if (bid >= a6.blk0) d = a6;
    else if (bid >= a5.blk0) d = a5;
    else if (bid >= a4.blk0) d = a4;
    else if (bid >= a3.blk0) d = a3;
    else if (bid >= a2.blk0) d = a2;
    else if (bid >= a1.blk0) d = a1;
    else                     d = a0;
    const int local = bid - d.blk0;
    const int nx = d.No >> 5;
    const int n0 = (local % nx) * 32, k0 = (local / nx) * 32;

    __shared__ float tb[32][33];
    const int tx = threadIdx.x & 31;
    const int ty = threadIdx.x >> 5;
#pragma unroll
    for (int qq = 0; qq < 4; ++qq)
        tb[ty + 8 * qq][tx] = d.W[(size_t)(k0 + ty + 8 * qq) * d.No + n0 + tx];
    __syncthreads();
#pragma unroll
    for (int qq = 0; qq < 4; ++qq)
        d.Wt[(size_t)(n0 + ty + 8 * qq) * d.K + k0 + tx] = f2b(tb[tx][ty + 8 * qq]);
}

// ---------------------------------------------------------------------------
// mm_k (128^2, round-2 structure) retained ONLY for sim (normalized, fp32 out)
// ---------------------------------------------------------------------------
__global__ __launch_bounds__(256) void simmm_k(
    const u16* __restrict__ A, const u16* __restrict__ Bt,
    const float* __restrict__ nf, const float* __restrict__ np_,
    float* __restrict__ Cout)
{
    __shared__ __align__(16) u16 Asm[4096];
    __shared__ __align__(16) u16 Bsm[4096];
    const int tid = threadIdx.x;
    const int wave = tid >> 6, lane = tid & 63;
    const int row0 = blockIdx.y * 128;
    const int cC0 = blockIdx.x * 128;
    const int brow0 = (row0 >> 8) * Nn + cC0;
    const int lda = D2, K = D2, ldc = Nn;

    const int la = lane >> 2, q = lane & 3;
    const u16* pA0[2]; const u16* pB0[2];
    char* dstA[2]; char* dstB[2];
#pragma unroll
    for (int i = 0; i < 2; ++i) {
        int c = wave * 2 + i;
        int r = c * 16 + la;
        int sp = q ^ ((r >> 1) & 3);
        pA0[i] = A + (size_t)(row0 + r) * lda + sp * 8;
        pB0[i] = Bt + (size_t)(brow0 + r) * K + sp * 8;
        dstA[i] = (char*)Asm + c * 1024;
        dstB[i] = (char*)Bsm + c * 1024;
    }

    const int wr = wave >> 1, wc = wave & 1;
    int aoff[4], boff[4];   // BYTE offsets
#pragma unroll
    for (int m = 0; m < 4; ++m) {
        int r = wr * 64 + m * 16 + (lane & 15);
        aoff[m] = r * 64 + (((lane >> 4) ^ ((r >> 1) & 3)) << 4);
    }
#pragma unroll
    for (int n = 0; n < 4; ++n) {
        int c = wc * 64 + n * 16 + (lane & 15);
        boff[n] = c * 64 + (((lane >> 4) ^ ((c >> 1) & 3)) << 4);
    }

    f32x4 acc[4][4] = {};
    for (int k0 = 0; k0 < K; k0 += 32) {
#pragma unroll
        for (int i = 0; i < 2; ++i) {
            gload16(pA0[i] + k0, dstA[i]);
            gload16(pB0[i] + k0, dstB[i]);
        }
        __syncthreads();
        bf16x8 av[4], bv[4];
#pragma unroll
        for (int m = 0; m < 4; ++m) av[m] = *(const bf16x8*)((const char*)Asm + aoff[m]);
#pragma unroll
        for (int n = 0; n < 4; ++n) bv[n] = *(const bf16x8*)((const char*)Bsm + boff[n]);
#pragma unroll
        for (int m = 0; m < 4; ++m)
#pragma unroll
            for (int n = 0; n < 4; ++n)
                acc[m][n] = __builtin_amdgcn_mfma_f32_16x16x32_bf16(av[m], bv[n], acc[m][n], 0, 0, 0);
        __syncthreads();
    }

    const int rb = row0 + wr * 64;
    const int cl = cC0 + wc * 64 + (lane & 15);
    float sj[4];
#pragma unroll
    for (int n = 0; n < 4; ++n)
        sj[n] = 1.f / fmaxf(np_[brow0 + wc * 64 + n * 16 + (lane & 15)], EPSN);
#pragma unroll
    for (int m = 0; m < 4; ++m)
#pragma unroll
        for (int n = 0; n < 4; ++n) {
            f32x4 v = acc[m][n];
#pragma unroll
            for (int rg = 0; rg < 4; ++rg) {
                int rr = rb + m * 16 + ((lane >> 4) << 2) + rg;
                float si = 1.f / fmaxf(nf[rr], EPSN);
                Cout[(size_t)rr * ldc + cl + n * 16] = v[rg] * si * sj[n];
            }
        }
}

// ---------------------------------------------------------------------------
// mmg_k: grouped 256x256 8-phase MFMA GEMM (two descriptor groups).
// ---------------------------------------------------------------------------
struct MMDesc {
    const u16* A; const u16* Aprev; const u16* zb; const int* midx;
    const u16* Bt; const float* bias; void* C;
    int lda, coff, K1, K, ldc, nwg;
};

template <int MODE, int RELU, int OUT>
__global__ __launch_bounds__(512, 2) void mmg_k(MMDesc da, MMDesc db, int split)
{
    __shared__ __align__(16) u16 smem[65536];   // 128 KiB
    char* ldsv = (char*)smem;

    const int bid = blockIdx.x;
    const MMDesc d = (bid < split) ? da : db;
    const int local = (bid < split) ? bid : (bid - split);

    const int tid = threadIdx.x;
    const int wave = tid >> 6, lane = tid & 63;
    const int l15 = lane & 15, l4 = lane >> 4;
    const int wr = wave >> 2, wc = wave & 3;

    // XCD-bijective swizzle within group
    const int nwg = d.nwg;
    const int xcd = local & 7, lid = local >> 3;
    const int qq = nwg >> 3, rr8 = nwg & 7;
    const int swz = (xcd < rr8 ? xcd * (qq + 1) : rr8 * (qq + 1) + (xcd - rr8) * qq) + lid;
    const int row0 = (swz & 31) * 256;
    const int col0 = (swz >> 5) * 256;

    const int K1 = d.K1, lda = d.lda, coff = d.coff, K = d.K;

    const u16* pA[2][2]; const u16* pA2[2][2]; const u16* pB[2][2];
    int cA8[2][2]; bool okA[2][2];
#pragma unroll
    for (int h = 0; h < 2; ++h)
#pragma unroll
        for (int i = 0; i < 2; ++i) {
            int lrow = (i * 512 + tid) >> 3;
            int r = h * 128 + lrow;
            int c = (tid & 7) ^ (lrow & 7);
            cA8[h][i] = c * 8;
            int grow = row0 + r;
            if (MODE == 0) {
                pA[h][i] = d.A + (size_t)grow * lda + c * 8;
                pA2[h][i] = nullptr; okA[h][i] = true;
            } else {
                pA[h][i] = d.A + (size_t)grow * lda + coff + c * 8;
                int jj = d.midx[grow];
                okA[h][i] = (jj >= 0);
                pA2[h][i] = okA[h][i]
                    ? (d.Aprev + (size_t)((grow & ~(Nn - 1)) + jj) * lda + coff + c * 8 - K1)
                    : (d.zb + c * 8);
            }
            pB[h][i] = d.Bt + (size_t)(col0 + r) * K + c * 8;
        }

#define STAGEA(h, kt, pp) do {                                                   \
    _Pragma("unroll")                                                            \
    for (int i_ = 0; i_ < 2; ++i_) {                                             \
        const u16* s_;                                                           \
        if (MODE == 0) s_ = pA[h][i_] + (kt);                                    \
        else {                                                                   \
            int gc_ = (kt) + cA8[h][i_];                                         \
            s_ = (gc_ < K1) ? (pA[h][i_] + (kt))                                 \
                            : (okA[h][i_] ? pA2[h][i_] + (kt) : pA2[h][i_]);     \
        }                                                                        \
        gload16(s_, ldsv + ((pp) * 32768 + (h) * 16384 + i_ * 8192 + wave * 1024)); \
    }                                                                            \
} while (0)

#define STAGEB(h, kt, pp) do {                                                   \
    _Pragma("unroll")                                                            \
    for (int i_ = 0; i_ < 2; ++i_)                                               \
        gload16(pB[h][i_] + (kt),                                                \
                ldsv + (65536 + (pp) * 32768 + (h) * 16384 + i_ * 8192 + wave * 1024)); \
} while (0)

    int aoffs[8][2], boffs[4][2];
#pragma unroll
    for (int m = 0; m < 8; ++m) {
        int r = m * 32 + wr * 16 + l15;
#pragma unroll
        for (int ks = 0; ks < 2; ++ks)
            aoffs[m][ks] = r * 128 + (((ks * 4 + l4) ^ (lane & 7)) << 4);
    }
#pragma unroll
    for (int n = 0; n < 4; ++n) {
        int r = n * 64 + wc * 16 + l15;
#pragma unroll
        for (int ks = 0; ks < 2; ++ks)
            boffs[n][ks] = r * 128 + (((ks * 4 + l4) ^ (lane & 7)) << 4);
    }

    bf16x8 avc[4][2], bvc[2][2];
    f32x4 acc[8][4] = {};

#define READA(mh, base) do {                                                     \
    _Pragma("unroll")                                                            \
    for (int m_ = 0; m_ < 4; ++m_) {                                             \
        avc[m_][0] = *(const bf16x8*)((base) + aoffs[(mh) * 4 + m_][0]);         \
        avc[m_][1] = *(const bf16x8*)((base) + aoffs[(mh) * 4 + m_][1]);         \
    }                                                                            \
} while (0)

#define READB(nh, base) do {                                                     \
    _Pragma("unroll")                                                            \
    for (int n_ = 0; n_ < 2; ++n_) {                                             \
        bvc[n_][0] = *(const bf16x8*)((base) + boffs[(nh) * 2 + n_][0]);         \
        bvc[n_][1] = *(const bf16x8*)((base) + boffs[(nh) * 2 + n_][1]);         \
    }                                                                            \
} while (0)

#define MFMA16(mh, nh) do {                                                      \
    _Pragma("unroll")                                                            \
    for (int ks_ = 0; ks_ < 2; ++ks_)                                            \
    _Pragma("unroll")                                                            \
    for (int m_ = 0; m_ < 4; ++m_)                                               \
    _Pragma("unroll")                                                            \
    for (int n_ = 0; n_ < 2; ++n_)                                               \
        acc[(mh) * 4 + m_][(nh) * 2 + n_] = __builtin_amdgcn_mfma_f32_16x16x32_bf16( \
            avc[m_][ks_], bvc[n_][ks_], acc[(mh) * 4 + m_][(nh) * 2 + n_], 0, 0, 0); \
} while (0)

    const int nt = K >> 6;

    STAGEA(0, 0, 0); STAGEB(0, 0, 0); STAGEA(1, 0, 0); STAGEB(1, 0, 0);

    int t = 0;
    for (; t < nt - 1; ++t) {
        const int p = t & 1;
        const char* bA = ldsv + p * 32768;
        const char* bB = ldsv + 65536 + p * 32768;
        const int kn = (t + 1) << 6;
        VMWAIT4; BAR();
        STAGEA(0, kn, p ^ 1);
        READA(0, bA); READB(0, bB);
        PRIO1; MFMA16(0, 0); PRIO0;
        VMWAIT4; BAR();
        STAGEB(0, kn, p ^ 1);
        READA(1, bA);
        PRIO1; MFMA16(1, 0); PRIO0;
        VMWAIT4; BAR();
        STAGEA(1, kn, p ^ 1);
        READB(1, bB);
        PRIO1; MFMA16(1, 1); PRIO0;
        BAR();
        STAGEB(1, kn, p ^ 1);
        READA(0, bA);
        PRIO1; MFMA16(0, 1); PRIO0;
    }
    {
        const int p = t & 1;
        const char* bA = ldsv + p * 32768;
        const char* bB = ldsv + 65536 + p * 32768;
        VMWAIT4; BAR(); READA(0, bA); READB(0, bB); PRIO1; MFMA16(0, 0); PRIO0;
        VMWAIT2; BAR(); READA(1, bA);               PRIO1; MFMA16(1, 0); PRIO0;
        VMWAIT0; BAR(); READB(1, bB);               PRIO1; MFMA16(1, 1); PRIO0;
        BAR();          READA(0, bA);               PRIO1; MFMA16(0, 1); PRIO0;
    }

#pragma unroll
    for (int n = 0; n < 4; ++n) {
        const int col = col0 + n * 64 + wc * 16 + l15;
        const float bz = d.bias[col];
#pragma unroll
        for (int m = 0; m < 8; ++m) {
#pragma unroll
            for (int rg = 0; rg < 4; ++rg) {
                int row = row0 + m * 32 + wr * 16 + l4 * 4 + rg;
                float x = acc[m][n][rg] + bz;
                if (RELU) x = fmaxf(x, 0.f);
                if (OUT == 0) ((u16*)d.C)[(size_t)row * d.ldc + col] = f2b(x);
                else          ((float*)d.C)[(size_t)row * d.ldc + col] = x;
            }
        }
    }
#undef STAGEA
#undef STAGEB
#undef READA
#undef READB
#undef MFMA16
}

// ---------------------------------------------------------------------------
// cand_k: per row (b,i), 256-bit candidate mask of j with mask && sim>=THRESH.
// Also defaults midx=-1, osp row = 0, and zeroes zbuf (block 0).
// ---------------------------------------------------------------------------
__global__ __launch_bounds__(256) void cand_k(
    const float* __restrict__ sim, const int* __restrict__ mask,
    u64* __restrict__ cand, int* __restrict__ midx,
    float* __restrict__ osp, float* __restrict__ zb)
{
    const int row = blockIdx.x, j = threadIdx.x;
    size_t off = (size_t)row * Nn + j;
    bool p = mask[off] && (sim[off] >= THRESH);
    u64 bal = __ballot(p);
    if ((j & 63) == 0) cand[row * 4 + (j >> 6)] = bal;
    if (j == 0) midx[row] = -1;
    if (j < SDIM) osp[(size_t)row * SDIM + j] = 0.f;
    if (row == 0) zb[j] = 0.f;
}

// ---------------------------------------------------------------------------
// matchseq_k: sequential greedy match, 1 wave per batch, no block barriers.
// Common path per row: LDS read + AND + __any. Rare path: argmax over set bits.
// ---------------------------------------------------------------------------
__global__ __launch_bounds__(64) void matchseq_k(
    const float* __restrict__ sim, const u64* __restrict__ cand,
    const float* __restrict__ psp, int* __restrict__ midx,
    float* __restrict__ osp)
{
    const int b = blockIdx.x;
    const int lane = threadIdx.x;
    __shared__ u64 cl[Nn * 4];
    for (int k = lane; k < Nn * 4; k += 64) cl[k] = cand[b * Nn * 4 + k];
    u64 vis = 0;   // meaningful on lanes 0..3 (word = lane)
    for (int i = 0; i < Nn; ++i) {
        u64 c = (lane < 4) ? (cl[i * 4 + lane] & ~vis) : 0ull;
        if (!__any(c != 0ull)) continue;
        // rare path: argmax over candidate bits (fp32 sim, first-index ties)
        u64 cw = __shfl(c, lane >> 4, 64);
        int basebit = (lane & 15) * 4;
        float best = -INFINITY; int bidx = Nn;
        const float* srow = sim + ((size_t)b * Nn + i) * Nn;
#pragma unroll
        for (int k = 0; k < 4; ++k) {
            if ((cw >> (basebit + k)) & 1ull) {
                int j = (lane >> 4) * 64 + basebit + k;
                float v = srow[j];
                if (v > best || (v == best && j < bidx)) { best = v; bidx = j; }
            }
        }
        for (int o = 32; o; o >>= 1) {
            float v2 = __shfl_down(best, o, 64);
            int i2 = __shfl_down(bidx, o, 64);
            if (v2 > best || (v2 == best && i2 < bidx)) { best = v2; bidx = i2; }
        }
        int jstar = __shfl(bidx, 0, 64);
        if (lane == (jstar >> 6)) vis |= 1ull << (jstar & 63);
        if (lane == 0) midx[b * Nn + i] = jstar;
        if (lane < SDIM)
            osp[((size_t)b * Nn + i) * SDIM + lane] = psp[((size_t)b * Nn + jstar) * SDIM + lane];
    }
}

// ---------------------------------------------------------------------------
// ln2_k: paired LayerNorm (img & pc) -> bf16 visb halves. grid (Mrows, 2).
// ---------------------------------------------------------------------------
__global__ __launch_bounds__(256) void ln2_k(
    const float* __restrict__ Xi, const float* __restrict__ gi, const float* __restrict__ bi,
    const float* __restrict__ Xp, const float* __restrict__ gp, const float* __restrict__ bp,
    u16* __restrict__ out)
{
    const int row = blockIdx.x, t = threadIdx.x;
    const float* X = blockIdx.y ? Xp : Xi;
    const float* g = blockIdx.y ? gp : gi;
    const float* be = blockIdx.y ? bp : bi;
    const int ooff = blockIdx.y ? VDIM : 0;
    float4 v = *(const float4*)(X + (size_t)row * VDIM + t * 4);
    float s = v.x + v.y + v.z + v.w;
    __shared__ float l4[4];
    for (int o = 32; o; o >>= 1) s += __shfl_down(s, o, 64);
    if ((t & 63) == 0) l4[t >> 6] = s;
    __syncthreads();
    float mean = (l4[0] + l4[1] + l4[2] + l4[3]) * (1.f / VDIM);
    __syncthreads();
    float dx = v.x - mean, dy = v.y - mean, dz = v.z - mean, dw = v.w - mean;
    float qv = dx * dx + dy * dy + dz * dz + dw * dw;
    for (int o = 32; o; o >>= 1) qv += __shfl_down(qv, o, 64);
    if ((t & 63) == 0) l4[t >> 6] = qv;
    __syncthreads();
    float var = (l4[0] + l4[1] + l4[2] + l4[3]) * (1.f / VDIM);
    float rstd = rsqrtf(var + LNEPS);
    float4 gv = *(const float4*)(g + t * 4);
    float4 bv = *(const float4*)(be + t * 4);
    *(ushort4*)(out + (size_t)row * 2048 + ooff + t * 4) = make_ushort4(
        f2b(dx * rstd * gv.x + bv.x), f2b(dy * rstd * gv.y + bv.y),
        f2b(dz * rstd * gv.z + bv.z), f2b(dw * rstd * gv.w + bv.w));
}

// final LN (fp32 out)
__global__ __launch_bounds__(256) void lnf_k(
    const float* __restrict__ X, const float* __restrict__ g,
    const float* __restrict__ be, float* __restrict__ out)
{
    const int row = blockIdx.x, t = threadIdx.x;
    float4 v = *(const float4*)(X + (size_t)row * VDIM + t * 4);
    float s = v.x + v.y + v.z + v.w;
    __shared__ float l4[4];
    for (int o = 32; o; o >>= 1) s += __shfl_down(s, o, 64);
    if ((t & 63) == 0) l4[t >> 6] = s;
    __syncthreads();
    float mean = (l4[0] + l4[1] + l4[2] + l4[3]) * (1.f / VDIM);
    __syncthreads();
    float dx = v.x - mean, dy = v.y - mean, dz = v.z - mean, dw = v.w - mean;
    float qv = dx * dx + dy * dy + dz * dz + dw * dw;
    for (int o = 32; o; o >>= 1) qv += __shfl_down(qv, o, 64);
    if ((t & 63) == 0) l4[t >> 6] = qv;
    __syncthreads();
    float var = (l4[0] + l4[1] + l4[2] + l4[3]) * (1.f / VDIM);
    float rstd = rsqrtf(var + LNEPS);
    float4 gv = *(const float4*)(g + t * 4);
    float4 bv = *(const float4*)(be + t * 4);
    *(float4*)(out + (size_t)row * VDIM + t * 4) = make_float4(
        dx * rstd * gv.x + bv.x, dy * rstd * gv.y + bv.y,
        dz * rstd * gv.z + bv.z, dw * rstd * gv.w + bv.w);
}

// ---------------------------------------------------------------------------
extern "C" void kernel_launch(void* const* d_in, const int* in_sizes, int n_in,
                              void* d_out, int out_size, void* d_ws, size_t ws_size,
                              hipStream_t stream)
{
    const float* image  = (const float*)d_in[0];
    const float* pcf    = (const float*)d_in[1];
    const float* pimage = (const float*)d_in[2];
    const float* ppcf   = (const float*)d_in[3];
    const float* psp    = (const float*)d_in[4];
    const int*   mask   = (const int*)d_in[5];
    const float* iw1 = (const float*)d_in[6];  const float* ib1 = (const float*)d_in[7];
    const float* iw2 = (const float*)d_in[8];  const float* ib2 = (const float*)d_in[9];
    const float* iw3 = (const float*)d_in[10]; const float* ib3 = (const float*)d_in[11];
    const float* ig  = (const float*)d_in[12]; const float* ibeta = (const float*)d_in[13];
    const float* pw1 = (const float*)d_in[14]; const float* pb1 = (const float*)d_in[15];
    const float* pw2 = (const float*)d_in[16]; const float* pb2 = (const float*)d_in[17];
    const float* pw3 = (const float*)d_in[18]; const float* pb3 = (const float*)d_in[19];
    const float* pg  = (const float*)d_in[20]; const float* pbeta = (const float*)d_in[21];
    const float* fw1 = (const float*)d_in[22]; const float* fb1 = (const float*)d_in[23];
    const float* fw2 = (const float*)d_in[24]; const float* fb2 = (const float*)d_in[25];
    const float* fg  = (const float*)d_in[26]; const float* fbeta = (const float*)d_in[27];

    float* out_vis = (float*)d_out;                        // [8192][1024]
    float* out_sp  = (float*)d_out + (size_t)Mrows * VDIM; // [8192][8]

    // ---- workspace carve (200.7 MB; lifetime-checked) ----
    char* wsb = (char*)d_ws;
    float* nf   = (float*)(wsb + 0);        // pack->sim; reused as zbuf after
    float* np_  = (float*)(wsb + 32768);
    int*   midx = (int*)(wsb + 65536);
    u64*   cand = (u64*)(wsb + 98304);      // 8192*4 u64 = 256 KB
    u16*   wt0  = (u16*)(wsb + 524288);     // weights region, 40.76 MB
    u16* iw1t = wt0;
    u16* iw2t = wt0 + 8388608;
    u16* iw3t = wt0 + 12582912;
    u16* pw1t = wt0 + 14680064;
    u16* pw2t = wt0 + 15859712;
    u16* pw3t = wt0 + 16449536;
    u16* fw1t = wt0 + 17235968;
    u16* fw2t = wt0 + 19333120;
    char* R1 = wsb + 41287680;   // 46.14 MB: featb; then h2b(@0)+ph2b(@32M)
    char* R2 = wsb + 87425024;   // 46.14 MB: pfeatb; then preLNimg(@0)
    char* R3 = wsb + 133562368;  // 33.55 MB: sim; h1b; visb; preLNf
    char* R4 = wsb + 167116800;  // 33.55 MB: ph1b; preLNpc; fh1b

    u16*   featb   = (u16*)R1;
    u16*   pfeatb  = (u16*)R2;
    float* sim     = (float*)R3;
    u16*   h1b     = (u16*)R3;
    u16*   ph1b    = (u16*)R4;
    u16*   h2b     = (u16*)R1;
    u16*   ph2b    = (u16*)(R1 + 33554432);
    float* preLNimg = (float*)R2;
    float* preLNpc  = (float*)R4;
    u16*   visb    = (u16*)R3;
    u16*   fh1b    = (u16*)R4;
    float* preLNf  = (float*)R3;
    float* zbuf    = nf;

    // 1. pack + norms
    pack_k<<<dim3(Mrows, 2), 256, 0, stream>>>(image, pcf, pimage, ppcf,
                                               featb, pfeatb, nf, np_);
    // 2. all weight transposes (one launch)
    {
        TD t0 = { iw1, iw1t, 2 * IDIM, IDIM, 0 };      // 64x128  = 8192
        TD t1 = { iw2, iw2t, IDIM, IDIM, 8192 };       // 64x64   = 4096
        TD t2 = { iw3, iw3t, IDIM, VDIM, 12288 };      // 32x64   = 2048
        TD t3 = { pw1, pw1t, 2 * PDIM, PDIM, 14336 };  // 24x48   = 1152
        TD t4 = { pw2, pw2t, PDIM, PDIM, 15488 };      // 24x24   = 576
        TD t5 = { pw3, pw3t, PDIM, VDIM, 16064 };      // 32x24   = 768
        TD t6 = { fw1, fw1t, 2048, VDIM, 16832 };      // 32x64   = 2048
        TD t7 = { fw2, fw2t, VDIM, VDIM, 18880 };      // 32x32   = 1024 -> 19904
        twtg_k<<<dim3(19904), 256, 0, stream>>>(t0, t1, t2, t3, t4, t5, t6, t7);
    }
    // 3. similarity
    simmm_k<<<dim3(2, 64), 256, 0, stream>>>(featb, pfeatb, nf, np_, sim);
    // 4. candidate masks (+ defaults + zbuf)
    cand_k<<<dim3(Mrows), 256, 0, stream>>>(sim, mask, cand, midx, out_sp, zbuf);
    // 5. sequential greedy match (1 wave per batch)
    matchseq_k<<<dim3(Bn), 64, 0, stream>>>(sim, cand, psp, midx, out_sp);

    // 6. depth-1: img1 + pc1 grouped
    {
        MMDesc di = { featb, pfeatb, (const u16*)zbuf, midx, iw1t, ib1, h1b,
                      D2, 0, IDIM, 2 * IDIM, IDIM, 256 };
        MMDesc dp = { featb, pfeatb, (const u16*)zbuf, midx, pw1t, pb1, ph1b,
                      D2, IDIM, PDIM, 2 * PDIM, PDIM, 96 };
        mmg_k<1, 1, 0><<<dim3(352), 512, 0, stream>>>(di, dp, 256);
    }
    // 7. depth-2: img2 + pc2 grouped
    {
        MMDesc di = { h1b, nullptr, nullptr, nullptr, iw2t, ib2, h2b,
                      IDIM, 0, 0, IDIM, IDIM, 256 };
        MMDesc dp = { ph1b, nullptr, nullptr, nullptr, pw2t, pb2, ph2b,
                      PDIM, 0, 0, PDIM, PDIM, 96 };
        mmg_k<0, 0, 0><<<dim3(352), 512, 0, stream>>>(di, dp, 256);
    }
    // 8. depth-3: img3 + pc3 grouped (fp32 out)
    {
        MMDesc di = { h2b, nullptr, nullptr, nullptr, iw3t, ib3, preLNimg,
                      IDIM, 0, 0, IDIM, VDIM, 128 };
        MMDesc dp = { ph2b, nullptr, nullptr, nullptr, pw3t, pb3, preLNpc,
                      PDIM, 0, 0, PDIM, VDIM, 128 };
        mmg_k<0, 0, 1><<<dim3(256), 512, 0, stream>>>(di, dp, 128);
    }
    // 9. paired LN -> visb
    ln2_k<<<dim3(Mrows, 2), 256, 0, stream>>>(preLNimg, ig, ibeta,
                                              preLNpc, pg, pbeta, visb);
    // 10. fused branch
    {
        MMDesc df = { visb, nullptr, nullptr, nullptr, fw1t, fb1, fh1b,
                      2048, 0, 0, 2048, VDIM, 128 };
        mmg_k<0, 1, 0><<<dim3(128), 512, 0, stream>>>(df, df, 128);
    }
    {
        MMDesc df = { fh1b, nullptr, nullptr, nullptr, fw2t, fb2, preLNf,
                      VDIM, 0, 0, VDIM, VDIM, 128 };
        mmg_k<0, 0, 1><<<dim3(128), 512, 0, stream>>>(df, df, 128);
    }
    lnf_k<<<dim3(Mrows), 256, 0, stream>>>(preLNf, fg, fbeta, out_vis);
}